// Round 4
// baseline (255.539 us; speedup 1.0000x reference)
//
#include <hip/hip_runtime.h>
#include <hip/hip_bf16.h>

#define B_SZ   2
#define SEQ    1024
#define DMODEL 1024
#define DINNER 2048
#define DSTATE 16
#define DCONV  4
#define DTRANK 64
#define BLROWS (B_SZ*SEQ)
#define NCHUNK 32
#define TCHUNK (SEQ/NCHUNK) // 32
#define NSLICE 16           // dbc split-K partials
#define LOG2E 1.44269504088896f

using floatx4 = __attribute__((ext_vector_type(4))) float;
using short8  = __attribute__((ext_vector_type(8))) short;
using us8     = __attribute__((ext_vector_type(8))) unsigned short;
using us4     = __attribute__((ext_vector_type(4))) unsigned short;

__device__ __forceinline__ float softplus_f(float x) {
    return fmaxf(x, 0.f) + log1pf(__expf(-fabsf(x)));
}
__device__ __forceinline__ float silu_f(float x) {
    return x / (1.f + __expf(-x));
}
__device__ __forceinline__ short bfs(float x) {
    union { __hip_bfloat16 h; short s; } u;
    u.h = __float2bfloat16(x);
    return u.s;
}
__device__ __forceinline__ float b2f(unsigned short s) {
    union { float f; unsigned u; } x;
    x.u = ((unsigned)s) << 16;
    return x.f;
}
__device__ __forceinline__ void gld16(const void* g, void* l) {
    __builtin_amdgcn_global_load_lds((const __attribute__((address_space(1))) void*)g,
                                     (__attribute__((address_space(3))) void*)l,
                                     16, 0, 0);
}
__device__ __forceinline__ void cast8(const float* src, unsigned short* dst, int i) {
    const float* p = src + (size_t)i*8;
    float4 a = *(const float4*)p, b = *(const float4*)(p+4);
    us8 o;
    o[0]=(unsigned short)bfs(a.x); o[1]=(unsigned short)bfs(a.y);
    o[2]=(unsigned short)bfs(a.z); o[3]=(unsigned short)bfs(a.w);
    o[4]=(unsigned short)bfs(b.x); o[5]=(unsigned short)bfs(b.y);
    o[6]=(unsigned short)bfs(b.z); o[7]=(unsigned short)bfs(b.w);
    *(us8*)(dst + (size_t)i*8) = o;
}

// ---------- fused init: 5 casts, range-partitioned ----------
#define G0 (BLROWS*DMODEL/8)       // x cast
#define G1 (2*DINNER*DMODEL/8)     // W_in cast
#define G2 (96*DINNER/8)           // W_x cast
#define G3 (DINNER*DTRANK/8)       // W_dt cast
#define G4 (DMODEL*DINNER/8)       // W_out cast
#define GTOT (G0+G1+G2+G3+G4)
__global__ __launch_bounds__(256)
void init_kernel(const float* __restrict__ x, const float* __restrict__ W_in,
                 const float* __restrict__ W_x, const float* __restrict__ W_dt,
                 const float* __restrict__ W_out,
                 unsigned short* xH, unsigned short* WinH, unsigned short* WxH,
                 unsigned short* WdtH, unsigned short* WoutH)
{
    int i = blockIdx.x*256 + threadIdx.x;
    if (i < G0) { cast8(x, xH, i); return; }            i -= G0;
    if (i < G1) { cast8(W_in, WinH, i); return; }       i -= G1;
    if (i < G2) { cast8(W_x, WxH, i); return; }         i -= G2;
    if (i < G3) { cast8(W_dt, WdtH, i); return; }       i -= G3;
    if (i < G4) { cast8(W_out, WoutH, i); }
}

// ---------- TN MFMA GEMM, double-buffered 2-phase K-loop, tile 128 x TN, BK=32 ----------
// EPI: 5 = split col<DINNER -> outH else outH2 (ld DINNER), bf16
//      8 = softplus(v + bias[col]) -> transposed bf16 packed (us4)
//      9 = plain f32 store to outF + blockIdx.z*M*N (partials / direct out)
template<int TN, int EPI, bool NGUARD>
__global__ __launch_bounds__(256)
void gemm_tn(const __hip_bfloat16* __restrict__ Ag, const __hip_bfloat16* __restrict__ Bg,
             int M, int N, int K, int kslice,
             float* __restrict__ outF,
             __hip_bfloat16* __restrict__ outH,
             __hip_bfloat16* __restrict__ outH2,
             const float* __restrict__ bias)
{
    constexpr int EB  = TN/64;        // B-tile 64-row groups
    constexpr int FNW = TN/32;        // frag-cols per wave
    __shared__ short As[2][128*32];
    __shared__ short Bs[2][TN*32];

    const int tid  = threadIdx.x;
    const int lane = tid & 63, wave = tid >> 6;
    const int bm0  = blockIdx.x * 128;
    const int bn0  = blockIdx.y * TN;
    const int kbeg = blockIdx.z * kslice;
    const int kend = kbeg + kslice;
    const int wrow = (wave >> 1) * 64, wcol = (wave & 1) * (TN/2);
    const int lrow = lane & 15, quad = lane >> 4;

    const int srow = wave*16 + (lane >> 2);
    const int scol = (lane & 3) * 8;

    const __hip_bfloat16* ga0 = Ag + (size_t)(bm0 + srow)*K      + scol;
    const __hip_bfloat16* ga1 = Ag + (size_t)(bm0 + srow + 64)*K + scol;
    const __hip_bfloat16* gb0 = Bg + (size_t)(bn0 + srow)*K      + scol;
    const __hip_bfloat16* gb1 = (EB > 1) ? Bg + (size_t)(bn0 + srow + 64)*K + scol : nullptr;
    const bool b0ok = !NGUARD || (bn0 + wave*16) < N;       // wave-uniform (16-row granules)
    const bool b1ok = (EB > 1) && (!NGUARD || (bn0 + wave*16 + 64) < N);

    auto stage = [&](int c, int k0) {
        gld16(ga0 + k0, &As[c][(wave*16)*32]);
        gld16(ga1 + k0, &As[c][(wave*16 + 64)*32]);
        if (b0ok) gld16(gb0 + k0, &Bs[c][(wave*16)*32]);
        if (EB > 1 && b1ok) gld16(gb1 + k0, &Bs[c][(wave*16 + 64)*32]);
    };

    floatx4 acc[4][FNW] = {};

    // prologue: stage first tile, drain, then 2-phase loop (one barrier per K-step)
    stage(0, kbeg);
    __syncthreads();
    int cur = 0;
    for (int k0 = kbeg; k0 < kend; k0 += 32) {
        if (k0 + 32 < kend) stage(cur ^ 1, k0 + 32);   // next-tile loads in flight
        short8 af[4], bf[FNW];
        #pragma unroll
        for (int i = 0; i < 4; i++)
            af[i] = *(const short8*)&As[cur][(wrow + i*16 + lrow)*32 + quad*8];
        #pragma unroll
        for (int j = 0; j < FNW; j++)
            bf[j] = *(const short8*)&Bs[cur][(wcol + j*16 + lrow)*32 + quad*8];
        #pragma unroll
        for (int i = 0; i < 4; i++)
            #pragma unroll
            for (int j = 0; j < FNW; j++)
                acc[i][j] = __builtin_amdgcn_mfma_f32_16x16x32_bf16(af[i], bf[j], acc[i][j], 0, 0, 0);
        __syncthreads();   // drains next-tile loads (they had MFMA time to land)
        cur ^= 1;
    }

    const int rq = quad * 4;
    #pragma unroll
    for (int i = 0; i < 4; i++) {
        #pragma unroll
        for (int j = 0; j < FNW; j++) {
            int col = bn0 + wcol + j*16 + lrow;
            if (NGUARD && col >= N) continue;
            if constexpr (EPI == 8) {
                int row0 = bm0 + wrow + i*16 + rq;
                int bb = row0 >> 10, ll = row0 & (SEQ-1);
                us4 pk;
                #pragma unroll
                for (int r = 0; r < 4; r++)
                    pk[r] = (unsigned short)bfs(softplus_f(acc[i][j][r] + bias[col]));
                *(us4*)((unsigned short*)outH + ((size_t)bb*DINNER + col)*SEQ + ll) = pk;
            } else {
                #pragma unroll
                for (int r = 0; r < 4; r++) {
                    int row = bm0 + wrow + i*16 + rq + r;
                    float v = acc[i][j][r];
                    if constexpr (EPI == 5) {
                        if (col < DINNER)
                            outH[(size_t)row*DINNER + col] = __float2bfloat16(v);
                        else
                            outH2[(size_t)row*DINNER + (col - DINNER)] = __float2bfloat16(v);
                    } else if constexpr (EPI == 9) {
                        outF[(size_t)blockIdx.z*M*N + (size_t)row*N + col] = v;
                    }
                }
            }
        }
    }
}

// ---------- dbc split-K reduce + dt cvt (fused) ----------
__global__ __launch_bounds__(192)
void dbc_reduce_kernel(const float* __restrict__ part, float* __restrict__ dbc,
                       __hip_bfloat16* __restrict__ dtH)
{
    const int tid = threadIdx.x;
    const int r2  = (tid >= 96) ? 1 : 0;
    const int col = tid - 96*r2;
    const int row = blockIdx.x*2 + r2;
    const size_t idx = (size_t)row*96 + col;
    float s = 0.f;
    #pragma unroll
    for (int z = 0; z < NSLICE; z++)
        s += part[(size_t)z*(BLROWS*96) + idx];
    dbc[idx] = s;
    if (col < DTRANK)
        dtH[(size_t)row*DTRANK + col] = __float2bfloat16(s);
}

// ---------- fused conv+silu+transpose: xbufN -> xsN (normal) + xsT (transposed) ----------
__global__ __launch_bounds__(256)
void conv_transpose_kernel(const unsigned short* __restrict__ xbufN,
                           const float* __restrict__ cw,
                           const float* __restrict__ cb,
                           unsigned short* __restrict__ xsN,
                           unsigned short* __restrict__ xsT)
{
    __shared__ unsigned short t[67*68];    // rows l0-3 .. l0+63
    __shared__ unsigned short t2[64*68];
    const int tid = threadIdx.x;
    const int l0 = blockIdx.x * 64, d0 = blockIdx.y * 64, b = blockIdx.z;

    const int lc4 = (tid & 15) * 4;
    for (int r = tid >> 4; r < 67; r += 16) {
        int lg = l0 - 3 + r;
        us4 v = {0,0,0,0};
        if (lg >= 0)
            v = *(const us4*)&xbufN[((size_t)(b*SEQ + lg))*DINNER + d0 + lc4];
        *(us4*)&t[r*68 + lc4] = v;
    }
    __syncthreads();

    const int dd = tid & 63;
    float4 w4 = *(const float4*)&cw[(d0 + dd)*4];
    float  bb = cb[d0 + dd];
    #pragma unroll 4
    for (int rr = tid >> 6; rr < 64; rr += 4) {
        float acc = bb;
        acc += w4.x * b2f(t[(rr+0)*68 + dd]);
        acc += w4.y * b2f(t[(rr+1)*68 + dd]);
        acc += w4.z * b2f(t[(rr+2)*68 + dd]);
        acc += w4.w * b2f(t[(rr+3)*68 + dd]);
        unsigned short h = (unsigned short)bfs(silu_f(acc));
        t2[rr*68 + dd] = h;
        xsN[((size_t)(b*SEQ + l0 + rr))*DINNER + d0 + dd] = h;
    }
    __syncthreads();

    const int dr = tid >> 4, lc = tid & 15;
    #pragma unroll
    for (int i = 0; i < 4; i++) {
        int dT = dr + i*16;
        us4 w;
        #pragma unroll
        for (int j = 0; j < 4; j++)
            w[j] = t2[(lc*4 + j)*68 + dT];
        *(us4*)&xsT[((size_t)b*DINNER + d0 + dT)*SEQ + l0 + lc*4] = w;
    }
}

// ========== chunked selective scan ==========
// grid: B_SZ * NCHUNK * 32 blocks; dg = blk&31, c = (blk>>5)&(NCHUNK-1), b = blk>>10
// An pre-scaled by log2(e) so the recurrence uses bare v_exp_f32 (exp2f)

// pass1: chunk-local recurrence from h=0; emits y_loc = C*h_local + u*D (f32),
// final chunk state h -> Bc, and sde = sum(de) over the chunk.
__global__ __launch_bounds__(256)
void scan_pass1(const unsigned short* __restrict__ deT,
                const unsigned short* __restrict__ xsT,
                const float* __restrict__ dbc,
                const float* __restrict__ A_log,
                const float* __restrict__ Dp,
                float* __restrict__ ylocF,
                float* __restrict__ Bc, float* __restrict__ sde)
{
    __shared__ float bcs[TCHUNK*32];         // B|C rows of this chunk
    const int tid  = threadIdx.x;
    const int q    = tid & 3, dsub = tid >> 2;
    const int blk  = blockIdx.x;
    const int dg   = blk & 31;
    const int c    = (blk >> 5) & (NCHUNK-1);
    const int b    = blk >> 10;
    const int d    = dg*64 + dsub;

    size_t b96 = (size_t)b*SEQ*96;
    {                                        // 256 threads stage 32 rows x 32 floats
        int r = tid >> 3, f = (tid & 7) * 4;
        *(float4*)&bcs[r*32 + f] =
            *(const float4*)&dbc[b96 + (size_t)(c*TCHUNK + r)*96 + DTRANK + f];
    }

    float An[4];
    *(float4*)An = *(const float4*)&A_log[d*DSTATE + 4*q];
    #pragma unroll
    for (int j = 0; j < 4; j++) An[j] = -__expf(An[j]) * LOG2E;
    const float Dd = Dp[d];

    size_t rowT  = ((size_t)b*DINNER + d)*SEQ;
    size_t baseN = (size_t)b*SEQ*DINNER + d;
    __syncthreads();

    float h[4] = {0.f,0.f,0.f,0.f};
    float s = 0.f;
    for (int t8 = 0; t8 < TCHUNK/8; ++t8) {
        int l0 = c*TCHUNK + t8*8;
        us8 de8 = *(const us8*)&deT[rowT + l0];
        us8 u8  = *(const us8*)&xsT[rowT + l0];
        #pragma unroll
        for (int j2 = 0; j2 < 8; j2++) {
            int l  = l0 + j2;
            int lr = t8*8 + j2;
            float Bn[4], Cn[4];
            *(float4*)Bn = *(const float4*)&bcs[lr*32 + 4*q];        // LDS broadcast
            *(float4*)Cn = *(const float4*)&bcs[lr*32 + 16 + 4*q];
            float de = b2f(de8[j2]);
            float u  = b2f(u8[j2]);
            float du = de * u;
            float cc = 0.f;
            #pragma unroll
            for (int j = 0; j < 4; j++) {
                h[j] = exp2f(de*An[j])*h[j] + du*Bn[j];
                cc += h[j]*Cn[j];
            }
            s += de;
            cc += __shfl_xor(cc, 1);
            cc += __shfl_xor(cc, 2);
            if (q == 0)
                ylocF[baseN + (size_t)l*DINNER] = cc + u*Dd;
        }
    }
    size_t ci = (size_t)(b*NCHUNK + c)*DINNER + d;
    *(float4*)&Bc[ci*16 + 4*q] = *(float4*)h;
    if (q == 0) sde[ci] = s;
}

__global__ __launch_bounds__(256)
void scan_pass2(float* __restrict__ Bc, const float* __restrict__ sde,
                const float* __restrict__ A_log)
{
    const int tid = threadIdx.x;
    const int n   = tid & 15, dl = tid >> 4;
    const int blk = blockIdx.x;
    const int dg  = blk & 127, b = blk >> 7;
    const int d   = dg*16 + dl;
    const float An = -__expf(A_log[d*DSTATE + n]) * LOG2E;

    float H = 0.f;
    for (int c = 0; c < NCHUNK; ++c) {
        size_t ci = (size_t)(b*NCHUNK + c)*DINNER + d;
        float bc = Bc[ci*16 + n];
        Bc[ci*16 + n] = H;
        H = exp2f(An*sde[ci])*H + bc;
    }
}

// pass3': correction-only. y = (y_loc + sum_n C_t[n]*exp(An*s_t)*H0[n]) * silu(z)
// where s_t = running cumsum of de within the chunk (inclusive).
__global__ __launch_bounds__(256)
void scan_pass3(const unsigned short* __restrict__ deT,
                const float* __restrict__ dbc,
                const float* __restrict__ A_log,
                const float* __restrict__ Hinit,
                const float* __restrict__ ylocF,
                const unsigned short* __restrict__ zN,
                __hip_bfloat16* __restrict__ yN)
{
    __shared__ float cs[TCHUNK*16];          // C rows of this chunk
    const int tid  = threadIdx.x;
    const int q    = tid & 3, dsub = tid >> 2;
    const int blk  = blockIdx.x;
    const int dg   = blk & 31;
    const int c    = (blk >> 5) & (NCHUNK-1);
    const int b    = blk >> 10;
    const int d    = dg*64 + dsub;

    size_t b96 = (size_t)b*SEQ*96;
    if (tid < TCHUNK*4) {                    // 128 threads stage 32 rows x 16 floats
        int r = tid >> 2, f = (tid & 3) * 4;
        *(float4*)&cs[r*16 + f] =
            *(const float4*)&dbc[b96 + (size_t)(c*TCHUNK + r)*96 + DTRANK + DSTATE + f];
    }

    float An[4];
    *(float4*)An = *(const float4*)&A_log[d*DSTATE + 4*q];
    #pragma unroll
    for (int j = 0; j < 4; j++) An[j] = -__expf(An[j]) * LOG2E;

    float H0[4];
    *(float4*)H0 = *(const float4*)&Hinit[((size_t)(b*NCHUNK + c)*DINNER + d)*16 + 4*q];

    size_t rowT  = ((size_t)b*DINNER + d)*SEQ;
    size_t baseN = (size_t)b*SEQ*DINNER + d;
    __syncthreads();

    float s = 0.f;
    for (int t8 = 0; t8 < TCHUNK/8; ++t8) {
        int l0 = c*TCHUNK + t8*8;
        us8 de8 = *(const us8*)&deT[rowT + l0];
        #pragma unroll
        for (int j2 = 0; j2 < 8; j2++) {
            int l  = l0 + j2;
            int lr = t8*8 + j2;
            float Cn[4];
            *(float4*)Cn = *(const float4*)&cs[lr*16 + 4*q];   // LDS broadcast
            s += b2f(de8[j2]);
            float corr = 0.f;
            #pragma unroll
            for (int j = 0; j < 4; j++)
                corr += Cn[j] * (exp2f(An[j]*s) * H0[j]);
            corr += __shfl_xor(corr, 1);
            corr += __shfl_xor(corr, 2);
            if (q == 0) {
                float yl = ylocF[baseN + (size_t)l*DINNER];
                float zv = silu_f(b2f(zN[baseN + (size_t)l*DINNER]));
                yN[baseN + (size_t)l*DINNER] = __float2bfloat16((yl + corr) * zv);
            }
        }
    }
}

// ---------- diagnostic fallback ----------
__global__ __launch_bounds__(256)
void zero_out_kernel(float* out, int n) {
    int i = blockIdx.x * 256 + threadIdx.x;
    if (i < n) out[i] = 0.f;
}

extern "C" void kernel_launch(void* const* d_in, const int* in_sizes, int n_in,
                              void* d_out, int out_size, void* d_ws, size_t ws_size,
                              hipStream_t stream) {
    const float* x      = (const float*)d_in[0];
    const float* W_in   = (const float*)d_in[1];
    const float* conv_w = (const float*)d_in[2];
    const float* conv_b = (const float*)d_in[3];
    const float* W_x    = (const float*)d_in[4];
    const float* W_dt   = (const float*)d_in[5];
    const float* b_dt   = (const float*)d_in[6];
    const float* A_log  = (const float*)d_in[7];
    const float* D_par  = (const float*)d_in[8];
    const float* W_out  = (const float*)d_in[9];

    size_t szBig = (size_t)BLROWS * DINNER * 2;                   // 8.39 MB
    size_t szBc  = (size_t)B_SZ * NCHUNK * DINNER * DSTATE * 4;   // 8.39 MB
    size_t szYl  = (size_t)BLROWS * DINNER * 4;                   // 16.8 MB
    size_t need  = 5*szBig                       // xbufN,zbufN,xsN,xsT,deT
                 + (size_t)BLROWS*96*4                        // dbc
                 + (size_t)NSLICE*BLROWS*96*4                 // dbc partials
                 + (size_t)BLROWS*DTRANK*2                    // dtH
                 + szBc + (size_t)B_SZ*NCHUNK*DINNER*4
                 + szYl                                       // y_loc f32
                 + (size_t)BLROWS*DMODEL*2       // xH
                 + (size_t)2*DINNER*DMODEL*2     // WinH
                 + (size_t)128*DINNER*2          // WxH
                 + (size_t)DINNER*DTRANK*2       // WdtH
                 + (size_t)DMODEL*DINNER*2;      // WoutH   (~108 MB, ws is ~268 MB)

    if (ws_size < need) {
        zero_out_kernel<<<(out_size + 255)/256, 256, 0, stream>>>((float*)d_out, out_size);
        return;
    }

    char* w = (char*)d_ws;
    __hip_bfloat16* xbufN = (__hip_bfloat16*)w;  w += szBig;
    __hip_bfloat16* zbufN = (__hip_bfloat16*)w;  w += szBig;
    __hip_bfloat16* xsN   = (__hip_bfloat16*)w;  w += szBig;   // later y (in-place)
    __hip_bfloat16* xsT   = (__hip_bfloat16*)w;  w += szBig;
    __hip_bfloat16* deT   = (__hip_bfloat16*)w;  w += szBig;
    float*          dbc   = (float*)w;           w += (size_t)BLROWS * 96 * 4;
    float*          dbcP  = (float*)w;           w += (size_t)NSLICE * BLROWS * 96 * 4;
    __hip_bfloat16* dtH   = (__hip_bfloat16*)w;  w += (size_t)BLROWS * DTRANK * 2;
    float*          Bc    = (float*)w;           w += szBc;
    float*          sde   = (float*)w;           w += (size_t)B_SZ * NCHUNK * DINNER * 4;
    float*          ylocF = (float*)w;           w += szYl;
    __hip_bfloat16* xH    = (__hip_bfloat16*)w;  w += (size_t)BLROWS*DMODEL*2;
    __hip_bfloat16* WinH  = (__hip_bfloat16*)w;  w += (size_t)2*DINNER*DMODEL*2;
    __hip_bfloat16* WxH   = (__hip_bfloat16*)w;  w += (size_t)128*DINNER*2;
    __hip_bfloat16* WdtH  = (__hip_bfloat16*)w;  w += (size_t)DINNER*DTRANK*2;
    __hip_bfloat16* WoutH = (__hip_bfloat16*)w;  w += (size_t)DMODEL*DINNER*2;
    __hip_bfloat16* yN    = xsN;

    // 0) fused init: all casts
    init_kernel<<<GTOT/256, 256, 0, stream>>>(x, W_in, W_x, W_dt, W_out,
        (unsigned short*)xH, (unsigned short*)WinH, (unsigned short*)WxH,
        (unsigned short*)WdtH, (unsigned short*)WoutH);

    // 1) xz = x @ W_in^T -> xbufN | zbufN. 128x128 tiles, 512 blocks (2/CU)
    gemm_tn<128,5,false><<<dim3(BLROWS/128, (2*DINNER)/128, 1), 256, 0, stream>>>(
        xH, WinH, BLROWS, 2*DINNER, DMODEL, DMODEL, nullptr, xbufN, zbufN, nullptr);

    // 2) fused conv+silu+transpose: xbufN -> xsN + xsT
    conv_transpose_kernel<<<dim3(SEQ/64, DINNER/64, B_SZ), 256, 0, stream>>>(
        (const unsigned short*)xbufN, conv_w, conv_b,
        (unsigned short*)xsN, (unsigned short*)xsT);

    // 3) dbc partials = x_ssm @ W_x^T (N=96, split-K=16, plain stores; 512 blocks)
    //    then fused reduce + dt cvt
    gemm_tn<64,9,true><<<dim3(BLROWS/128, 2, NSLICE), 256, 0, stream>>>(
        xsN, WxH, BLROWS, 96, DINNER, DINNER/NSLICE, dbcP, nullptr, nullptr, nullptr);
    dbc_reduce_kernel<<<BLROWS/2, 192, 0, stream>>>(dbcP, dbc, dtH);

    // 4) delta = softplus(dt @ W_dt^T + b_dt) -> deT (transposed). 512 blocks
    gemm_tn<64,8,false><<<dim3(BLROWS/128, DINNER/64, 1), 256, 0, stream>>>(
        dtH, WdtH, BLROWS, DINNER, DTRANK, DTRANK, nullptr, deT, nullptr, b_dt);

    // 5) chunked selective scan: pass1 emits y_loc; pass3' adds the H0 correction
    //    and gates. 2048 blocks = 8/CU
    scan_pass1<<<B_SZ*NCHUNK*32, 256, 0, stream>>>((const unsigned short*)deT,
        (const unsigned short*)xsT, dbc, A_log, D_par, ylocF, Bc, sde);
    scan_pass2<<<B_SZ*128, 256, 0, stream>>>(Bc, sde, A_log);
    scan_pass3<<<B_SZ*NCHUNK*32, 256, 0, stream>>>((const unsigned short*)deT,
        dbc, A_log, Bc, ylocF, (const unsigned short*)zbufN, yN);

    // 6) out = y @ W_out^T -> d_out. Direct f32 stores, no split-K (R2 config;
    //    R3's split-K+reduce was a measured +8.6us regression)
    gemm_tn<64,9,false><<<dim3(BLROWS/128, DMODEL/64, 1), 256, 0, stream>>>(
        yN, WoutH, BLROWS, DMODEL, DINNER, DINNER, (float*)d_out, nullptr, nullptr, nullptr);
}

// Round 5
// 233.317 us; speedup vs baseline: 1.0952x; 1.0952x over previous
//
#include <hip/hip_runtime.h>
#include <hip/hip_bf16.h>

#define B_SZ   2
#define SEQ    1024
#define DMODEL 1024
#define DINNER 2048
#define DSTATE 16
#define DCONV  4
#define DTRANK 64
#define BLROWS (B_SZ*SEQ)
#define NCHUNK 32
#define TCHUNK (SEQ/NCHUNK) // 32
#define NSLICE 16           // dbc split-K partials
#define LOG2E 1.44269504088896f

using floatx4 = __attribute__((ext_vector_type(4))) float;
using short8  = __attribute__((ext_vector_type(8))) short;
using us8     = __attribute__((ext_vector_type(8))) unsigned short;
using us4     = __attribute__((ext_vector_type(4))) unsigned short;

__device__ __forceinline__ float softplus_f(float x) {
    return fmaxf(x, 0.f) + log1pf(__expf(-fabsf(x)));
}
__device__ __forceinline__ float silu_f(float x) {
    return x / (1.f + __expf(-x));
}
__device__ __forceinline__ short bfs(float x) {
    union { __hip_bfloat16 h; short s; } u;
    u.h = __float2bfloat16(x);
    return u.s;
}
__device__ __forceinline__ float b2f(unsigned short s) {
    union { float f; unsigned u; } x;
    x.u = ((unsigned)s) << 16;
    return x.f;
}
__device__ __forceinline__ void gld16(const void* g, void* l) {
    __builtin_amdgcn_global_load_lds((const __attribute__((address_space(1))) void*)g,
                                     (__attribute__((address_space(3))) void*)l,
                                     16, 0, 0);
}
__device__ __forceinline__ void cast8(const float* src, unsigned short* dst, int i) {
    const float* p = src + (size_t)i*8;
    float4 a = *(const float4*)p, b = *(const float4*)(p+4);
    us8 o;
    o[0]=(unsigned short)bfs(a.x); o[1]=(unsigned short)bfs(a.y);
    o[2]=(unsigned short)bfs(a.z); o[3]=(unsigned short)bfs(a.w);
    o[4]=(unsigned short)bfs(b.x); o[5]=(unsigned short)bfs(b.y);
    o[6]=(unsigned short)bfs(b.z); o[7]=(unsigned short)bfs(b.w);
    *(us8*)(dst + (size_t)i*8) = o;
}

// ---------- fused init: 5 casts, range-partitioned ----------
#define G0 (BLROWS*DMODEL/8)       // x cast
#define G1 (2*DINNER*DMODEL/8)     // W_in cast
#define G2 (96*DINNER/8)           // W_x cast
#define G3 (DINNER*DTRANK/8)       // W_dt cast
#define G4 (DMODEL*DINNER/8)       // W_out cast
#define GTOT (G0+G1+G2+G3+G4)
__global__ __launch_bounds__(256)
void init_kernel(const float* __restrict__ x, const float* __restrict__ W_in,
                 const float* __restrict__ W_x, const float* __restrict__ W_dt,
                 const float* __restrict__ W_out,
                 unsigned short* xH, unsigned short* WinH, unsigned short* WxH,
                 unsigned short* WdtH, unsigned short* WoutH)
{
    int i = blockIdx.x*256 + threadIdx.x;
    if (i < G0) { cast8(x, xH, i); return; }            i -= G0;
    if (i < G1) { cast8(W_in, WinH, i); return; }       i -= G1;
    if (i < G2) { cast8(W_x, WxH, i); return; }         i -= G2;
    if (i < G3) { cast8(W_dt, WdtH, i); return; }       i -= G3;
    if (i < G4) { cast8(W_out, WoutH, i); }
}

// ---------- TN MFMA GEMM, double-buffered 2-phase K-loop, tile TM x TN, BK=32 ----------
// EPI: 5 = split col<DINNER -> outH else outH2 (ld DINNER), bf16
//      8 = softplus(v + bias[col]) -> transposed bf16 packed (us4)
//      9 = plain f32 store to outF + blockIdx.z*M*N (partials / direct out)
template<int TM, int TN, int EPI, bool NGUARD>
__global__ __launch_bounds__(256)
void gemm_tn(const __hip_bfloat16* __restrict__ Ag, const __hip_bfloat16* __restrict__ Bg,
             int M, int N, int K, int kslice,
             float* __restrict__ outF,
             __hip_bfloat16* __restrict__ outH,
             __hip_bfloat16* __restrict__ outH2,
             const float* __restrict__ bias)
{
    constexpr int AG  = TM/64;        // A-tile 64-row stage groups
    constexpr int EB  = TN/64;        // B-tile 64-row stage groups
    constexpr int MF  = TM/32;        // frag-rows per wave
    constexpr int NF  = TN/32;        // frag-cols per wave
    __shared__ short As[2][TM*32];
    __shared__ short Bs[2][TN*32];

    const int tid  = threadIdx.x;
    const int lane = tid & 63, wave = tid >> 6;
    const int bm0  = blockIdx.x * TM;
    const int bn0  = blockIdx.y * TN;
    const int kbeg = blockIdx.z * kslice;
    const int kend = kbeg + kslice;
    const int wrow = (wave >> 1) * (TM/2), wcol = (wave & 1) * (TN/2);
    const int lrow = lane & 15, quad = lane >> 4;

    const int srow = wave*16 + (lane >> 2);
    const int scol = (lane & 3) * 8;

    const __hip_bfloat16* ga0 = Ag + (size_t)(bm0 + srow)*K      + scol;
    const __hip_bfloat16* ga1 = (AG > 1) ? Ag + (size_t)(bm0 + srow + 64)*K + scol : nullptr;
    const __hip_bfloat16* gb0 = Bg + (size_t)(bn0 + srow)*K      + scol;
    const __hip_bfloat16* gb1 = (EB > 1) ? Bg + (size_t)(bn0 + srow + 64)*K + scol : nullptr;
    const bool b0ok = !NGUARD || (bn0 + wave*16) < N;       // wave-uniform (16-row granules)
    const bool b1ok = (EB > 1) && (!NGUARD || (bn0 + wave*16 + 64) < N);

    auto stage = [&](int c, int k0) {
        gld16(ga0 + k0, &As[c][(wave*16)*32]);
        if (AG > 1) gld16(ga1 + k0, &As[c][(wave*16 + 64)*32]);
        if (b0ok) gld16(gb0 + k0, &Bs[c][(wave*16)*32]);
        if (EB > 1 && b1ok) gld16(gb1 + k0, &Bs[c][(wave*16 + 64)*32]);
    };

    floatx4 acc[MF][NF] = {};

    // prologue: stage first tile, drain, then 2-phase loop (one barrier per K-step)
    stage(0, kbeg);
    __syncthreads();
    int cur = 0;
    for (int k0 = kbeg; k0 < kend; k0 += 32) {
        if (k0 + 32 < kend) stage(cur ^ 1, k0 + 32);   // next-tile loads in flight
        short8 af[MF], bf[NF];
        #pragma unroll
        for (int i = 0; i < MF; i++)
            af[i] = *(const short8*)&As[cur][(wrow + i*16 + lrow)*32 + quad*8];
        #pragma unroll
        for (int j = 0; j < NF; j++)
            bf[j] = *(const short8*)&Bs[cur][(wcol + j*16 + lrow)*32 + quad*8];
        #pragma unroll
        for (int i = 0; i < MF; i++)
            #pragma unroll
            for (int j = 0; j < NF; j++)
                acc[i][j] = __builtin_amdgcn_mfma_f32_16x16x32_bf16(af[i], bf[j], acc[i][j], 0, 0, 0);
        __syncthreads();   // drains next-tile loads (they had MFMA time to land)
        cur ^= 1;
    }

    const int rq = quad * 4;
    #pragma unroll
    for (int i = 0; i < MF; i++) {
        #pragma unroll
        for (int j = 0; j < NF; j++) {
            int col = bn0 + wcol + j*16 + lrow;
            if (NGUARD && col >= N) continue;
            if constexpr (EPI == 8) {
                int row0 = bm0 + wrow + i*16 + rq;
                int bb = row0 >> 10, ll = row0 & (SEQ-1);
                us4 pk;
                #pragma unroll
                for (int r = 0; r < 4; r++)
                    pk[r] = (unsigned short)bfs(softplus_f(acc[i][j][r] + bias[col]));
                *(us4*)((unsigned short*)outH + ((size_t)bb*DINNER + col)*SEQ + ll) = pk;
            } else {
                #pragma unroll
                for (int r = 0; r < 4; r++) {
                    int row = bm0 + wrow + i*16 + rq + r;
                    float v = acc[i][j][r];
                    if constexpr (EPI == 5) {
                        if (col < DINNER)
                            outH[(size_t)row*DINNER + col] = __float2bfloat16(v);
                        else
                            outH2[(size_t)row*DINNER + (col - DINNER)] = __float2bfloat16(v);
                    } else if constexpr (EPI == 9) {
                        outF[(size_t)blockIdx.z*M*N + (size_t)row*N + col] = v;
                    }
                }
            }
        }
    }
}

// ---------- dbc split-K reduce + dt cvt (fused) ----------
__global__ __launch_bounds__(192)
void dbc_reduce_kernel(const float* __restrict__ part, float* __restrict__ dbc,
                       __hip_bfloat16* __restrict__ dtH)
{
    const int tid = threadIdx.x;
    const int r2  = (tid >= 96) ? 1 : 0;
    const int col = tid - 96*r2;
    const int row = blockIdx.x*2 + r2;
    const size_t idx = (size_t)row*96 + col;
    float s = 0.f;
    #pragma unroll
    for (int z = 0; z < NSLICE; z++)
        s += part[(size_t)z*(BLROWS*96) + idx];
    dbc[idx] = s;
    if (col < DTRANK)
        dtH[(size_t)row*DTRANK + col] = __float2bfloat16(s);
}

// ---------- fused conv+silu+transpose: xbufN -> xsN (normal) + xsT (transposed) ----------
__global__ __launch_bounds__(256)
void conv_transpose_kernel(const unsigned short* __restrict__ xbufN,
                           const float* __restrict__ cw,
                           const float* __restrict__ cb,
                           unsigned short* __restrict__ xsN,
                           unsigned short* __restrict__ xsT)
{
    __shared__ unsigned short t[67*68];    // rows l0-3 .. l0+63
    __shared__ unsigned short t2[64*68];
    const int tid = threadIdx.x;
    const int l0 = blockIdx.x * 64, d0 = blockIdx.y * 64, b = blockIdx.z;

    const int lc4 = (tid & 15) * 4;
    for (int r = tid >> 4; r < 67; r += 16) {
        int lg = l0 - 3 + r;
        us4 v = {0,0,0,0};
        if (lg >= 0)
            v = *(const us4*)&xbufN[((size_t)(b*SEQ + lg))*DINNER + d0 + lc4];
        *(us4*)&t[r*68 + lc4] = v;
    }
    __syncthreads();

    const int dd = tid & 63;
    float4 w4 = *(const float4*)&cw[(d0 + dd)*4];
    float  bb = cb[d0 + dd];
    #pragma unroll 4
    for (int rr = tid >> 6; rr < 64; rr += 4) {
        float acc = bb;
        acc += w4.x * b2f(t[(rr+0)*68 + dd]);
        acc += w4.y * b2f(t[(rr+1)*68 + dd]);
        acc += w4.z * b2f(t[(rr+2)*68 + dd]);
        acc += w4.w * b2f(t[(rr+3)*68 + dd]);
        unsigned short h = (unsigned short)bfs(silu_f(acc));
        t2[rr*68 + dd] = h;
        xsN[((size_t)(b*SEQ + l0 + rr))*DINNER + d0 + dd] = h;
    }
    __syncthreads();

    const int dr = tid >> 4, lc = tid & 15;
    #pragma unroll
    for (int i = 0; i < 4; i++) {
        int dT = dr + i*16;
        us4 w;
        #pragma unroll
        for (int j = 0; j < 4; j++)
            w[j] = t2[(lc*4 + j)*68 + dT];
        *(us4*)&xsT[((size_t)b*DINNER + d0 + dT)*SEQ + l0 + lc*4] = w;
    }
}

// ========== chunked selective scan, hybrid lanes ==========
// grid: B_SZ * NCHUNK * 32 blocks; dg = blk&31, c = (blk>>5)&(NCHUNK-1), b = blk>>10
// Fast path: A[d][n] == -(n+1) (A_log = log(arange(1..16)) broadcast), verified at
// runtime per-wave; exp(de*A[n]) = r^(n+1), r = exp2(-de*LOG2E) -> 1 exp instead of 4.
__global__ __launch_bounds__(256)
void scan_pass1(const unsigned short* __restrict__ deT,
                const unsigned short* __restrict__ xsT,
                const float* __restrict__ dbc,
                const float* __restrict__ A_log,
                float* __restrict__ Bc, float* __restrict__ sde)
{
    __shared__ float bs[TCHUNK*16];          // B rows of this chunk
    const int tid  = threadIdx.x;
    const int q    = tid & 3, dsub = tid >> 2;
    const int blk  = blockIdx.x;
    const int dg   = blk & 31;
    const int c    = (blk >> 5) & (NCHUNK-1);
    const int b    = blk >> 10;
    const int d    = dg*64 + dsub;

    size_t b96 = (size_t)b*SEQ*96;
    if (tid < TCHUNK*4) {                    // 128 threads stage 32 rows x 16 floats
        int r = tid >> 2, f = (tid & 3) * 4;
        *(float4*)&bs[r*16 + f] =
            *(const float4*)&dbc[b96 + (size_t)(c*TCHUNK + r)*96 + DTRANK + f];
    }

    float An[4];
    *(float4*)An = *(const float4*)&A_log[d*DSTATE + 4*q];
    bool okv = true;
    #pragma unroll
    for (int j = 0; j < 4; j++) {
        An[j] = -__expf(An[j]) * LOG2E;
        okv = okv && (fabsf(An[j] + (float)(4*q + j + 1) * LOG2E) < 2e-3f * (float)(4*q + j + 1));
    }
    const bool fast = __all((int)okv);

    size_t rowT = ((size_t)b*DINNER + d)*SEQ;
    __syncthreads();

    float h[4] = {0.f,0.f,0.f,0.f};
    float s = 0.f;
    if (fast) {
        for (int t8 = 0; t8 < TCHUNK/8; ++t8) {
            int l0 = c*TCHUNK + t8*8;
            us8 de8 = *(const us8*)&deT[rowT + l0];
            us8 u8  = *(const us8*)&xsT[rowT + l0];
            #pragma unroll
            for (int j2 = 0; j2 < 8; j2++) {
                int lr = t8*8 + j2;
                float Bn[4];
                *(float4*)Bn = *(const float4*)&bs[lr*16 + 4*q];   // LDS broadcast
                float de = b2f(de8[j2]);
                float du = de * b2f(u8[j2]);
                float r  = exp2f(de * (-LOG2E));
                float r2 = r*r, r4 = r2*r2, r8 = r4*r4;
                float rb = ((q & 2) ? r8 : 1.0f) * ((q & 1) ? r4 : 1.0f);
                float e0 = rb*r, e1 = e0*r, e2 = e1*r, e3 = e2*r;
                h[0] = e0*h[0] + du*Bn[0];
                h[1] = e1*h[1] + du*Bn[1];
                h[2] = e2*h[2] + du*Bn[2];
                h[3] = e3*h[3] + du*Bn[3];
                s += de;
            }
        }
    } else {
        for (int t8 = 0; t8 < TCHUNK/8; ++t8) {
            int l0 = c*TCHUNK + t8*8;
            us8 de8 = *(const us8*)&deT[rowT + l0];
            us8 u8  = *(const us8*)&xsT[rowT + l0];
            #pragma unroll
            for (int j2 = 0; j2 < 8; j2++) {
                int lr = t8*8 + j2;
                float Bn[4];
                *(float4*)Bn = *(const float4*)&bs[lr*16 + 4*q];
                float de = b2f(de8[j2]);
                float du = de * b2f(u8[j2]);
                #pragma unroll
                for (int j = 0; j < 4; j++)
                    h[j] = exp2f(de*An[j])*h[j] + du*Bn[j];
                s += de;
            }
        }
    }
    size_t ci = (size_t)(b*NCHUNK + c)*DINNER + d;
    *(float4*)&Bc[ci*16 + 4*q] = *(float4*)h;
    if (q == 0) sde[ci] = s;
}

__global__ __launch_bounds__(256)
void scan_pass2(float* __restrict__ Bc, const float* __restrict__ sde,
                const float* __restrict__ A_log)
{
    const int tid = threadIdx.x;
    const int n   = tid & 15, dl = tid >> 4;
    const int blk = blockIdx.x;
    const int dg  = blk & 127, b = blk >> 7;
    const int d   = dg*16 + dl;
    const float An = -__expf(A_log[d*DSTATE + n]) * LOG2E;

    float H = 0.f;
    for (int c = 0; c < NCHUNK; ++c) {
        size_t ci = (size_t)(b*NCHUNK + c)*DINNER + d;
        float bc = Bc[ci*16 + n];
        Bc[ci*16 + n] = H;
        H = exp2f(An*sde[ci])*H + bc;
    }
}

// pass3 fuses the gate: y = (scan_out + u*D) * silu(z)
__global__ __launch_bounds__(256)
void scan_pass3(const unsigned short* __restrict__ deT,
                const unsigned short* __restrict__ xsT,
                const float* __restrict__ dbc,
                const float* __restrict__ A_log,
                const float* __restrict__ Dp,
                const float* __restrict__ Hinit,
                const unsigned short* __restrict__ zN,
                __hip_bfloat16* __restrict__ yN)
{
    __shared__ float bcs[TCHUNK*32];         // B|C rows of this chunk
    const int tid  = threadIdx.x;
    const int q    = tid & 3, dsub = tid >> 2;
    const int blk  = blockIdx.x;
    const int dg   = blk & 31;
    const int c    = (blk >> 5) & (NCHUNK-1);
    const int b    = blk >> 10;
    const int d    = dg*64 + dsub;

    size_t b96 = (size_t)b*SEQ*96;
    {                                        // 256 threads stage 32 rows x 32 floats
        int r = tid >> 3, f = (tid & 7) * 4;
        *(float4*)&bcs[r*32 + f] =
            *(const float4*)&dbc[b96 + (size_t)(c*TCHUNK + r)*96 + DTRANK + f];
    }

    float An[4];
    *(float4*)An = *(const float4*)&A_log[d*DSTATE + 4*q];
    bool okv = true;
    #pragma unroll
    for (int j = 0; j < 4; j++) {
        An[j] = -__expf(An[j]) * LOG2E;
        okv = okv && (fabsf(An[j] + (float)(4*q + j + 1) * LOG2E) < 2e-3f * (float)(4*q + j + 1));
    }
    const bool fast = __all((int)okv);
    const float Dd = Dp[d];

    size_t rowT  = ((size_t)b*DINNER + d)*SEQ;
    size_t baseN = (size_t)b*SEQ*DINNER + d;

    float h[4];
    *(float4*)h = *(const float4*)&Hinit[((size_t)(b*NCHUNK + c)*DINNER + d)*16 + 4*q];
    __syncthreads();

    if (fast) {
        for (int t8 = 0; t8 < TCHUNK/8; ++t8) {
            int l0 = c*TCHUNK + t8*8;
            us8 de8 = *(const us8*)&deT[rowT + l0];
            us8 u8  = *(const us8*)&xsT[rowT + l0];
            #pragma unroll
            for (int j2 = 0; j2 < 8; j2++) {
                int l  = l0 + j2;
                int lr = t8*8 + j2;
                float Bn[4], Cn[4];
                *(float4*)Bn = *(const float4*)&bcs[lr*32 + 4*q];        // LDS broadcast
                *(float4*)Cn = *(const float4*)&bcs[lr*32 + 16 + 4*q];
                float de = b2f(de8[j2]);
                float u  = b2f(u8[j2]);
                float du = de * u;
                float r  = exp2f(de * (-LOG2E));
                float r2 = r*r, r4 = r2*r2, r8 = r4*r4;
                float rb = ((q & 2) ? r8 : 1.0f) * ((q & 1) ? r4 : 1.0f);
                float e0 = rb*r, e1 = e0*r, e2 = e1*r, e3 = e2*r;
                h[0] = e0*h[0] + du*Bn[0];
                h[1] = e1*h[1] + du*Bn[1];
                h[2] = e2*h[2] + du*Bn[2];
                h[3] = e3*h[3] + du*Bn[3];
                float cc = h[0]*Cn[0] + h[1]*Cn[1] + h[2]*Cn[2] + h[3]*Cn[3];
                cc += __shfl_xor(cc, 1);
                cc += __shfl_xor(cc, 2);
                if (q == 0) {
                    float zv = silu_f(b2f(zN[baseN + (size_t)l*DINNER]));
                    yN[baseN + (size_t)l*DINNER] = __float2bfloat16((cc + u*Dd) * zv);
                }
            }
        }
    } else {
        for (int t8 = 0; t8 < TCHUNK/8; ++t8) {
            int l0 = c*TCHUNK + t8*8;
            us8 de8 = *(const us8*)&deT[rowT + l0];
            us8 u8  = *(const us8*)&xsT[rowT + l0];
            #pragma unroll
            for (int j2 = 0; j2 < 8; j2++) {
                int l  = l0 + j2;
                int lr = t8*8 + j2;
                float Bn[4], Cn[4];
                *(float4*)Bn = *(const float4*)&bcs[lr*32 + 4*q];
                *(float4*)Cn = *(const float4*)&bcs[lr*32 + 16 + 4*q];
                float de = b2f(de8[j2]);
                float u  = b2f(u8[j2]);
                float du = de * u;
                float cc = 0.f;
                #pragma unroll
                for (int j = 0; j < 4; j++) {
                    h[j] = exp2f(de*An[j])*h[j] + du*Bn[j];
                    cc += h[j]*Cn[j];
                }
                cc += __shfl_xor(cc, 1);
                cc += __shfl_xor(cc, 2);
                if (q == 0) {
                    float zv = silu_f(b2f(zN[baseN + (size_t)l*DINNER]));
                    yN[baseN + (size_t)l*DINNER] = __float2bfloat16((cc + u*Dd) * zv);
                }
            }
        }
    }
}

// ---------- diagnostic fallback ----------
__global__ __launch_bounds__(256)
void zero_out_kernel(float* out, int n) {
    int i = blockIdx.x * 256 + threadIdx.x;
    if (i < n) out[i] = 0.f;
}

extern "C" void kernel_launch(void* const* d_in, const int* in_sizes, int n_in,
                              void* d_out, int out_size, void* d_ws, size_t ws_size,
                              hipStream_t stream) {
    const float* x      = (const float*)d_in[0];
    const float* W_in   = (const float*)d_in[1];
    const float* conv_w = (const float*)d_in[2];
    const float* conv_b = (const float*)d_in[3];
    const float* W_x    = (const float*)d_in[4];
    const float* W_dt   = (const float*)d_in[5];
    const float* b_dt   = (const float*)d_in[6];
    const float* A_log  = (const float*)d_in[7];
    const float* D_par  = (const float*)d_in[8];
    const float* W_out  = (const float*)d_in[9];

    size_t szBig = (size_t)BLROWS * DINNER * 2;                   // 8.39 MB
    size_t szBc  = (size_t)B_SZ * NCHUNK * DINNER * DSTATE * 4;   // 8.39 MB
    size_t need  = 5*szBig                       // xbufN,zbufN,xsN,xsT,deT
                 + (size_t)BLROWS*96*4                        // dbc
                 + (size_t)NSLICE*BLROWS*96*4                 // dbc partials
                 + (size_t)BLROWS*DTRANK*2                    // dtH
                 + szBc + (size_t)B_SZ*NCHUNK*DINNER*4
                 + (size_t)BLROWS*DMODEL*2       // xH
                 + (size_t)2*DINNER*DMODEL*2     // WinH
                 + (size_t)128*DINNER*2          // WxH
                 + (size_t)DINNER*DTRANK*2       // WdtH
                 + (size_t)DMODEL*DINNER*2;      // WoutH   (~83 MB, ws is ~268 MB)

    if (ws_size < need) {
        zero_out_kernel<<<(out_size + 255)/256, 256, 0, stream>>>((float*)d_out, out_size);
        return;
    }

    char* w = (char*)d_ws;
    __hip_bfloat16* xbufN = (__hip_bfloat16*)w;  w += szBig;
    __hip_bfloat16* zbufN = (__hip_bfloat16*)w;  w += szBig;
    __hip_bfloat16* xsN   = (__hip_bfloat16*)w;  w += szBig;   // later y (in-place)
    __hip_bfloat16* xsT   = (__hip_bfloat16*)w;  w += szBig;
    __hip_bfloat16* deT   = (__hip_bfloat16*)w;  w += szBig;
    float*          dbc   = (float*)w;           w += (size_t)BLROWS * 96 * 4;
    float*          dbcP  = (float*)w;           w += (size_t)NSLICE * BLROWS * 96 * 4;
    __hip_bfloat16* dtH   = (__hip_bfloat16*)w;  w += (size_t)BLROWS * DTRANK * 2;
    float*          Bc    = (float*)w;           w += szBc;
    float*          sde   = (float*)w;           w += (size_t)B_SZ * NCHUNK * DINNER * 4;
    __hip_bfloat16* xH    = (__hip_bfloat16*)w;  w += (size_t)BLROWS*DMODEL*2;
    __hip_bfloat16* WinH  = (__hip_bfloat16*)w;  w += (size_t)2*DINNER*DMODEL*2;
    __hip_bfloat16* WxH   = (__hip_bfloat16*)w;  w += (size_t)128*DINNER*2;
    __hip_bfloat16* WdtH  = (__hip_bfloat16*)w;  w += (size_t)DINNER*DTRANK*2;
    __hip_bfloat16* WoutH = (__hip_bfloat16*)w;  w += (size_t)DMODEL*DINNER*2;
    __hip_bfloat16* yN    = xsN;

    // 0) fused init: all casts
    init_kernel<<<GTOT/256, 256, 0, stream>>>(x, W_in, W_x, W_dt, W_out,
        (unsigned short*)xH, (unsigned short*)WinH, (unsigned short*)WxH,
        (unsigned short*)WdtH, (unsigned short*)WoutH);

    // 1) xz = x @ W_in^T -> xbufN | zbufN. 128x128 tiles, 512 blocks (2/CU)
    gemm_tn<128,128,5,false><<<dim3(BLROWS/128, (2*DINNER)/128, 1), 256, 0, stream>>>(
        xH, WinH, BLROWS, 2*DINNER, DMODEL, DMODEL, nullptr, xbufN, zbufN, nullptr);

    // 2) fused conv+silu+transpose: xbufN -> xsN + xsT
    conv_transpose_kernel<<<dim3(SEQ/64, DINNER/64, B_SZ), 256, 0, stream>>>(
        (const unsigned short*)xbufN, conv_w, conv_b,
        (unsigned short*)xsN, (unsigned short*)xsT);

    // 3) dbc partials = x_ssm @ W_x^T (N=96, split-K=16, plain stores; 512 blocks)
    //    then fused reduce + dt cvt
    gemm_tn<128,64,9,true><<<dim3(BLROWS/128, 2, NSLICE), 256, 0, stream>>>(
        xsN, WxH, BLROWS, 96, DINNER, DINNER/NSLICE, dbcP, nullptr, nullptr, nullptr);
    dbc_reduce_kernel<<<BLROWS/2, 192, 0, stream>>>(dbcP, dbc, dtH);

    // 4) delta = softplus(dt @ W_dt^T + b_dt) -> deT (transposed). 512 blocks
    gemm_tn<128,64,8,false><<<dim3(BLROWS/128, DINNER/64, 1), 256, 0, stream>>>(
        dtH, WdtH, BLROWS, DINNER, DTRANK, DTRANK, nullptr, deT, nullptr, b_dt);

    // 5) chunked selective scan (pass3 fuses gate). 2048 blocks = 8/CU
    scan_pass1<<<B_SZ*NCHUNK*32, 256, 0, stream>>>((const unsigned short*)deT,
        (const unsigned short*)xsT, dbc, A_log, Bc, sde);
    scan_pass2<<<B_SZ*128, 256, 0, stream>>>(Bc, sde, A_log);
    scan_pass3<<<B_SZ*NCHUNK*32, 256, 0, stream>>>((const unsigned short*)deT,
        (const unsigned short*)xsT, dbc, A_log, D_par, Bc,
        (const unsigned short*)zbufN, yN);

    // 6) out = y @ W_out^T -> d_out. 64x64 tiles -> 512 blocks (2/CU), direct f32 store
    gemm_tn<64,64,9,false><<<dim3(BLROWS/64, DMODEL/64, 1), 256, 0, stream>>>(
        yN, WoutH, BLROWS, DMODEL, DINNER, DINNER, (float*)d_out, nullptr, nullptr, nullptr);
}

// Round 6
// 229.807 us; speedup vs baseline: 1.1120x; 1.0153x over previous
//
#include <hip/hip_runtime.h>
#include <hip/hip_bf16.h>

#define B_SZ   2
#define SEQ    1024
#define DMODEL 1024
#define DINNER 2048
#define DSTATE 16
#define DCONV  4
#define DTRANK 64
#define BLROWS (B_SZ*SEQ)
#define NCHUNK 32
#define TCHUNK (SEQ/NCHUNK) // 32
#define NSLICE 16           // dbc split-K partials
#define LOG2E 1.44269504088896f

using floatx4 = __attribute__((ext_vector_type(4))) float;
using short8  = __attribute__((ext_vector_type(8))) short;
using us8     = __attribute__((ext_vector_type(8))) unsigned short;
using us4     = __attribute__((ext_vector_type(4))) unsigned short;

__device__ __forceinline__ float softplus_f(float x) {
    return fmaxf(x, 0.f) + log1pf(__expf(-fabsf(x)));
}
__device__ __forceinline__ float silu_f(float x) {
    return x / (1.f + __expf(-x));
}
__device__ __forceinline__ short bfs(float x) {
    union { __hip_bfloat16 h; short s; } u;
    u.h = __float2bfloat16(x);
    return u.s;
}
__device__ __forceinline__ float b2f(unsigned short s) {
    union { float f; unsigned u; } x;
    x.u = ((unsigned)s) << 16;
    return x.f;
}
__device__ __forceinline__ void gld16(const void* g, void* l) {
    __builtin_amdgcn_global_load_lds((const __attribute__((address_space(1))) void*)g,
                                     (__attribute__((address_space(3))) void*)l,
                                     16, 0, 0);
}
__device__ __forceinline__ void cast8(const float* src, unsigned short* dst, int i) {
    const float* p = src + (size_t)i*8;
    float4 a = *(const float4*)p, b = *(const float4*)(p+4);
    us8 o;
    o[0]=(unsigned short)bfs(a.x); o[1]=(unsigned short)bfs(a.y);
    o[2]=(unsigned short)bfs(a.z); o[3]=(unsigned short)bfs(a.w);
    o[4]=(unsigned short)bfs(b.x); o[5]=(unsigned short)bfs(b.y);
    o[6]=(unsigned short)bfs(b.z); o[7]=(unsigned short)bfs(b.w);
    *(us8*)(dst + (size_t)i*8) = o;
}

// ---------- fused init: 5 casts, range-partitioned ----------
#define G0 (BLROWS*DMODEL/8)       // x cast
#define G1 (2*DINNER*DMODEL/8)     // W_in cast
#define G2 (96*DINNER/8)           // W_x cast
#define G3 (DINNER*DTRANK/8)       // W_dt cast
#define G4 (DMODEL*DINNER/8)       // W_out cast
#define GTOT (G0+G1+G2+G3+G4)
__global__ __launch_bounds__(256)
void init_kernel(const float* __restrict__ x, const float* __restrict__ W_in,
                 const float* __restrict__ W_x, const float* __restrict__ W_dt,
                 const float* __restrict__ W_out,
                 unsigned short* xH, unsigned short* WinH, unsigned short* WxH,
                 unsigned short* WdtH, unsigned short* WoutH)
{
    int i = blockIdx.x*256 + threadIdx.x;
    if (i < G0) { cast8(x, xH, i); return; }            i -= G0;
    if (i < G1) { cast8(W_in, WinH, i); return; }       i -= G1;
    if (i < G2) { cast8(W_x, WxH, i); return; }         i -= G2;
    if (i < G3) { cast8(W_dt, WdtH, i); return; }       i -= G3;
    if (i < G4) { cast8(W_out, WoutH, i); }
}

// ---------- TN MFMA GEMM, double-buffered 2-phase K-loop, tile TM x TN, BK=32 ----------
// EPI: 5 = split col<DINNER -> outH else outH2 (ld DINNER), bf16
//      8 = softplus(v + bias[col]) -> transposed bf16 packed (us4)
//      9 = plain f32 store to outF + blockIdx.z*M*N (partials / direct out)
template<int TM, int TN, int EPI, bool NGUARD>
__global__ __launch_bounds__(256)
void gemm_tn(const __hip_bfloat16* __restrict__ Ag, const __hip_bfloat16* __restrict__ Bg,
             int M, int N, int K, int kslice,
             float* __restrict__ outF,
             __hip_bfloat16* __restrict__ outH,
             __hip_bfloat16* __restrict__ outH2,
             const float* __restrict__ bias)
{
    constexpr int AG  = TM/64;        // A-tile 64-row stage groups
    constexpr int EB  = TN/64;        // B-tile 64-row stage groups
    constexpr int MF  = TM/32;        // frag-rows per wave
    constexpr int NF  = TN/32;        // frag-cols per wave
    __shared__ short As[2][TM*32];
    __shared__ short Bs[2][TN*32];

    const int tid  = threadIdx.x;
    const int lane = tid & 63, wave = tid >> 6;
    const int bm0  = blockIdx.x * TM;
    const int bn0  = blockIdx.y * TN;
    const int kbeg = blockIdx.z * kslice;
    const int kend = kbeg + kslice;
    const int wrow = (wave >> 1) * (TM/2), wcol = (wave & 1) * (TN/2);
    const int lrow = lane & 15, quad = lane >> 4;

    const int srow = wave*16 + (lane >> 2);
    const int scol = (lane & 3) * 8;

    const __hip_bfloat16* ga0 = Ag + (size_t)(bm0 + srow)*K      + scol;
    const __hip_bfloat16* ga1 = (AG > 1) ? Ag + (size_t)(bm0 + srow + 64)*K + scol : nullptr;
    const __hip_bfloat16* gb0 = Bg + (size_t)(bn0 + srow)*K      + scol;
    const __hip_bfloat16* gb1 = (EB > 1) ? Bg + (size_t)(bn0 + srow + 64)*K + scol : nullptr;
    const bool b0ok = !NGUARD || (bn0 + wave*16) < N;       // wave-uniform (16-row granules)
    const bool b1ok = (EB > 1) && (!NGUARD || (bn0 + wave*16 + 64) < N);

    auto stage = [&](int c, int k0) {
        gld16(ga0 + k0, &As[c][(wave*16)*32]);
        if (AG > 1) gld16(ga1 + k0, &As[c][(wave*16 + 64)*32]);
        if (b0ok) gld16(gb0 + k0, &Bs[c][(wave*16)*32]);
        if (EB > 1 && b1ok) gld16(gb1 + k0, &Bs[c][(wave*16 + 64)*32]);
    };

    floatx4 acc[MF][NF] = {};

    // prologue: stage first tile, drain, then 2-phase loop (one barrier per K-step)
    stage(0, kbeg);
    __syncthreads();
    int cur = 0;
    for (int k0 = kbeg; k0 < kend; k0 += 32) {
        if (k0 + 32 < kend) stage(cur ^ 1, k0 + 32);   // next-tile loads in flight
        short8 af[MF], bf[NF];
        #pragma unroll
        for (int i = 0; i < MF; i++)
            af[i] = *(const short8*)&As[cur][(wrow + i*16 + lrow)*32 + quad*8];
        #pragma unroll
        for (int j = 0; j < NF; j++)
            bf[j] = *(const short8*)&Bs[cur][(wcol + j*16 + lrow)*32 + quad*8];
        #pragma unroll
        for (int i = 0; i < MF; i++)
            #pragma unroll
            for (int j = 0; j < NF; j++)
                acc[i][j] = __builtin_amdgcn_mfma_f32_16x16x32_bf16(af[i], bf[j], acc[i][j], 0, 0, 0);
        __syncthreads();   // drains next-tile loads (they had MFMA time to land)
        cur ^= 1;
    }

    const int rq = quad * 4;
    #pragma unroll
    for (int i = 0; i < MF; i++) {
        #pragma unroll
        for (int j = 0; j < NF; j++) {
            int col = bn0 + wcol + j*16 + lrow;
            if (NGUARD && col >= N) continue;
            if constexpr (EPI == 8) {
                int row0 = bm0 + wrow + i*16 + rq;
                int bb = row0 >> 10, ll = row0 & (SEQ-1);
                us4 pk;
                #pragma unroll
                for (int r = 0; r < 4; r++)
                    pk[r] = (unsigned short)bfs(softplus_f(acc[i][j][r] + bias[col]));
                *(us4*)((unsigned short*)outH + ((size_t)bb*DINNER + col)*SEQ + ll) = pk;
            } else {
                #pragma unroll
                for (int r = 0; r < 4; r++) {
                    int row = bm0 + wrow + i*16 + rq + r;
                    float v = acc[i][j][r];
                    if constexpr (EPI == 5) {
                        if (col < DINNER)
                            outH[(size_t)row*DINNER + col] = __float2bfloat16(v);
                        else
                            outH2[(size_t)row*DINNER + (col - DINNER)] = __float2bfloat16(v);
                    } else if constexpr (EPI == 9) {
                        outF[(size_t)blockIdx.z*M*N + (size_t)row*N + col] = v;
                    }
                }
            }
        }
    }
}

// ---------- dbc split-K reduce + dt cvt (fused) ----------
__global__ __launch_bounds__(192)
void dbc_reduce_kernel(const float* __restrict__ part, float* __restrict__ dbc,
                       __hip_bfloat16* __restrict__ dtH)
{
    const int tid = threadIdx.x;
    const int r2  = (tid >= 96) ? 1 : 0;
    const int col = tid - 96*r2;
    const int row = blockIdx.x*2 + r2;
    const size_t idx = (size_t)row*96 + col;
    float s = 0.f;
    #pragma unroll
    for (int z = 0; z < NSLICE; z++)
        s += part[(size_t)z*(BLROWS*96) + idx];
    dbc[idx] = s;
    if (col < DTRANK)
        dtH[(size_t)row*DTRANK + col] = __float2bfloat16(s);
}

// ---------- fused conv+silu+transpose: xbufN -> xsN (normal) + xsT (transposed) ----------
__global__ __launch_bounds__(256)
void conv_transpose_kernel(const unsigned short* __restrict__ xbufN,
                           const float* __restrict__ cw,
                           const float* __restrict__ cb,
                           unsigned short* __restrict__ xsN,
                           unsigned short* __restrict__ xsT)
{
    __shared__ unsigned short t[67*68];    // rows l0-3 .. l0+63
    __shared__ unsigned short t2[64*68];
    const int tid = threadIdx.x;
    const int l0 = blockIdx.x * 64, d0 = blockIdx.y * 64, b = blockIdx.z;

    const int lc4 = (tid & 15) * 4;
    for (int r = tid >> 4; r < 67; r += 16) {
        int lg = l0 - 3 + r;
        us4 v = {0,0,0,0};
        if (lg >= 0)
            v = *(const us4*)&xbufN[((size_t)(b*SEQ + lg))*DINNER + d0 + lc4];
        *(us4*)&t[r*68 + lc4] = v;
    }
    __syncthreads();

    const int dd = tid & 63;
    float4 w4 = *(const float4*)&cw[(d0 + dd)*4];
    float  bb = cb[d0 + dd];
    #pragma unroll 4
    for (int rr = tid >> 6; rr < 64; rr += 4) {
        float acc = bb;
        acc += w4.x * b2f(t[(rr+0)*68 + dd]);
        acc += w4.y * b2f(t[(rr+1)*68 + dd]);
        acc += w4.z * b2f(t[(rr+2)*68 + dd]);
        acc += w4.w * b2f(t[(rr+3)*68 + dd]);
        unsigned short h = (unsigned short)bfs(silu_f(acc));
        t2[rr*68 + dd] = h;
        xsN[((size_t)(b*SEQ + l0 + rr))*DINNER + d0 + dd] = h;
    }
    __syncthreads();

    const int dr = tid >> 4, lc = tid & 15;
    #pragma unroll
    for (int i = 0; i < 4; i++) {
        int dT = dr + i*16;
        us4 w;
        #pragma unroll
        for (int j = 0; j < 4; j++)
            w[j] = t2[(lc*4 + j)*68 + dT];
        *(us4*)&xsT[((size_t)b*DINNER + d0 + dT)*SEQ + l0 + lc*4] = w;
    }
}

// ========== chunked selective scan, one d-channel per lane ==========
// grid: B_SZ * NCHUNK * 8 blocks (512); dg = blk&7, c = (blk>>3)&(NCHUNK-1), b = blk>>8
// d = dg*256 + tid. No LDS, no shuffles: h[16] per lane (static unroll), B/C rows
// are wave-uniform -> scalar-pipe loads; z/y path fully coalesced (128B/wave/step).
// Fast path (A_log = log(arange(1..16)) broadcast, verified per-wave):
// exp(de*A[n]) = r^(n+1), r = exp2(-de*LOG2E) -> 1 transcendental + mul chain.
__global__ __launch_bounds__(256)
void scan_pass1(const unsigned short* __restrict__ deT,
                const unsigned short* __restrict__ xsT,
                const float* __restrict__ dbc,
                const float* __restrict__ A_log,
                float* __restrict__ Bc, float* __restrict__ sde)
{
    const int tid = threadIdx.x;
    const int blk = blockIdx.x;
    const int dg  = blk & 7;
    const int c   = (blk >> 3) & (NCHUNK-1);
    const int b   = blk >> 8;
    const int d   = dg*256 + tid;

    float An[16];
    bool okv = true;
    #pragma unroll
    for (int n = 0; n < 16; n++) {
        An[n] = -__expf(A_log[d*DSTATE + n]) * LOG2E;
        okv = okv && (fabsf(An[n] + (float)(n+1)*LOG2E) < 2e-3f*(float)(n+1));
    }
    const bool fast = __all((int)okv);

    size_t rowT = ((size_t)b*DINNER + d)*SEQ;
    const float* brow = dbc + (size_t)b*SEQ*96 + (size_t)(c*TCHUNK)*96 + DTRANK;

    float h[16];
    #pragma unroll
    for (int n = 0; n < 16; n++) h[n] = 0.f;
    float s = 0.f;

    if (fast) {
        for (int t8 = 0; t8 < TCHUNK/8; ++t8) {
            int l0 = c*TCHUNK + t8*8;
            us8 de8 = *(const us8*)&deT[rowT + l0];
            us8 u8  = *(const us8*)&xsT[rowT + l0];
            #pragma unroll
            for (int j2 = 0; j2 < 8; j2++) {
                const float* br = brow + (size_t)(t8*8 + j2)*96;   // wave-uniform
                float de = b2f(de8[j2]);
                float du = de * b2f(u8[j2]);
                float r  = exp2f(de * (-LOG2E));
                float e  = r;
                #pragma unroll
                for (int n = 0; n < 16; n++) {
                    h[n] = e*h[n] + du*br[n];
                    e *= r;
                }
                s += de;
            }
        }
    } else {
        for (int t8 = 0; t8 < TCHUNK/8; ++t8) {
            int l0 = c*TCHUNK + t8*8;
            us8 de8 = *(const us8*)&deT[rowT + l0];
            us8 u8  = *(const us8*)&xsT[rowT + l0];
            #pragma unroll
            for (int j2 = 0; j2 < 8; j2++) {
                const float* br = brow + (size_t)(t8*8 + j2)*96;
                float de = b2f(de8[j2]);
                float du = de * b2f(u8[j2]);
                #pragma unroll
                for (int n = 0; n < 16; n++)
                    h[n] = exp2f(de*An[n])*h[n] + du*br[n];
                s += de;
            }
        }
    }

    size_t ci = (size_t)(b*NCHUNK + c)*DINNER + d;
    #pragma unroll
    for (int n = 0; n < 16; n += 4) {
        float4 v; v.x = h[n]; v.y = h[n+1]; v.z = h[n+2]; v.w = h[n+3];
        *(float4*)&Bc[ci*16 + n] = v;
    }
    sde[ci] = s;
}

__global__ __launch_bounds__(256)
void scan_pass2(float* __restrict__ Bc, const float* __restrict__ sde,
                const float* __restrict__ A_log)
{
    const int tid = threadIdx.x;
    const int n   = tid & 15, dl = tid >> 4;
    const int blk = blockIdx.x;
    const int dg  = blk & 127, b = blk >> 7;
    const int d   = dg*16 + dl;
    const float An = -__expf(A_log[d*DSTATE + n]) * LOG2E;

    float H = 0.f;
    for (int c = 0; c < NCHUNK; ++c) {
        size_t ci = (size_t)(b*NCHUNK + c)*DINNER + d;
        float bc = Bc[ci*16 + n];
        Bc[ci*16 + n] = H;
        H = exp2f(An*sde[ci])*H + bc;
    }
}

// pass3: full recurrence seeded with Hinit, fused gate y = (cc + u*D) * silu(z)
__global__ __launch_bounds__(256)
void scan_pass3(const unsigned short* __restrict__ deT,
                const unsigned short* __restrict__ xsT,
                const float* __restrict__ dbc,
                const float* __restrict__ A_log,
                const float* __restrict__ Dp,
                const float* __restrict__ Hinit,
                const unsigned short* __restrict__ zN,
                __hip_bfloat16* __restrict__ yN)
{
    const int tid = threadIdx.x;
    const int blk = blockIdx.x;
    const int dg  = blk & 7;
    const int c   = (blk >> 3) & (NCHUNK-1);
    const int b   = blk >> 8;
    const int d   = dg*256 + tid;

    float An[16];
    bool okv = true;
    #pragma unroll
    for (int n = 0; n < 16; n++) {
        An[n] = -__expf(A_log[d*DSTATE + n]) * LOG2E;
        okv = okv && (fabsf(An[n] + (float)(n+1)*LOG2E) < 2e-3f*(float)(n+1));
    }
    const bool fast = __all((int)okv);
    const float Dd = Dp[d];

    size_t rowT  = ((size_t)b*DINNER + d)*SEQ;
    size_t baseN = (size_t)b*SEQ*DINNER + d;
    const float* brow = dbc + (size_t)b*SEQ*96 + (size_t)(c*TCHUNK)*96 + DTRANK;

    size_t ci = (size_t)(b*NCHUNK + c)*DINNER + d;
    float h[16];
    #pragma unroll
    for (int n = 0; n < 16; n += 4) {
        float4 v = *(const float4*)&Hinit[ci*16 + n];
        h[n] = v.x; h[n+1] = v.y; h[n+2] = v.z; h[n+3] = v.w;
    }

    if (fast) {
        for (int t8 = 0; t8 < TCHUNK/8; ++t8) {
            int l0 = c*TCHUNK + t8*8;
            us8 de8 = *(const us8*)&deT[rowT + l0];
            us8 u8  = *(const us8*)&xsT[rowT + l0];
            #pragma unroll
            for (int j2 = 0; j2 < 8; j2++) {
                int l = l0 + j2;
                const float* br = brow + (size_t)(t8*8 + j2)*96;   // wave-uniform
                float de = b2f(de8[j2]);
                float u  = b2f(u8[j2]);
                float du = de * u;
                float r  = exp2f(de * (-LOG2E));
                float e  = r, cc = 0.f;
                #pragma unroll
                for (int n = 0; n < 16; n++) {
                    h[n] = e*h[n] + du*br[n];
                    cc  += h[n]*br[DSTATE + n];
                    e   *= r;
                }
                float zv = silu_f(b2f(zN[baseN + (size_t)l*DINNER]));
                yN[baseN + (size_t)l*DINNER] = __float2bfloat16((cc + u*Dd) * zv);
            }
        }
    } else {
        for (int t8 = 0; t8 < TCHUNK/8; ++t8) {
            int l0 = c*TCHUNK + t8*8;
            us8 de8 = *(const us8*)&deT[rowT + l0];
            us8 u8  = *(const us8*)&xsT[rowT + l0];
            #pragma unroll
            for (int j2 = 0; j2 < 8; j2++) {
                int l = l0 + j2;
                const float* br = brow + (size_t)(t8*8 + j2)*96;
                float de = b2f(de8[j2]);
                float u  = b2f(u8[j2]);
                float du = de * u;
                float cc = 0.f;
                #pragma unroll
                for (int n = 0; n < 16; n++) {
                    h[n] = exp2f(de*An[n])*h[n] + du*br[n];
                    cc  += h[n]*br[DSTATE + n];
                }
                float zv = silu_f(b2f(zN[baseN + (size_t)l*DINNER]));
                yN[baseN + (size_t)l*DINNER] = __float2bfloat16((cc + u*Dd) * zv);
            }
        }
    }
}

// ---------- diagnostic fallback ----------
__global__ __launch_bounds__(256)
void zero_out_kernel(float* out, int n) {
    int i = blockIdx.x * 256 + threadIdx.x;
    if (i < n) out[i] = 0.f;
}

extern "C" void kernel_launch(void* const* d_in, const int* in_sizes, int n_in,
                              void* d_out, int out_size, void* d_ws, size_t ws_size,
                              hipStream_t stream) {
    const float* x      = (const float*)d_in[0];
    const float* W_in   = (const float*)d_in[1];
    const float* conv_w = (const float*)d_in[2];
    const float* conv_b = (const float*)d_in[3];
    const float* W_x    = (const float*)d_in[4];
    const float* W_dt   = (const float*)d_in[5];
    const float* b_dt   = (const float*)d_in[6];
    const float* A_log  = (const float*)d_in[7];
    const float* D_par  = (const float*)d_in[8];
    const float* W_out  = (const float*)d_in[9];

    size_t szBig = (size_t)BLROWS * DINNER * 2;                   // 8.39 MB
    size_t szBc  = (size_t)B_SZ * NCHUNK * DINNER * DSTATE * 4;   // 8.39 MB
    size_t need  = 5*szBig                       // xbufN,zbufN,xsN,xsT,deT
                 + (size_t)BLROWS*96*4                        // dbc
                 + (size_t)NSLICE*BLROWS*96*4                 // dbc partials
                 + (size_t)BLROWS*DTRANK*2                    // dtH
                 + szBc + (size_t)B_SZ*NCHUNK*DINNER*4
                 + (size_t)BLROWS*DMODEL*2       // xH
                 + (size_t)2*DINNER*DMODEL*2     // WinH
                 + (size_t)128*DINNER*2          // WxH
                 + (size_t)DINNER*DTRANK*2       // WdtH
                 + (size_t)DMODEL*DINNER*2;      // WoutH   (~83 MB, ws is ~268 MB)

    if (ws_size < need) {
        zero_out_kernel<<<(out_size + 255)/256, 256, 0, stream>>>((float*)d_out, out_size);
        return;
    }

    char* w = (char*)d_ws;
    __hip_bfloat16* xbufN = (__hip_bfloat16*)w;  w += szBig;
    __hip_bfloat16* zbufN = (__hip_bfloat16*)w;  w += szBig;
    __hip_bfloat16* xsN   = (__hip_bfloat16*)w;  w += szBig;   // later y (in-place)
    __hip_bfloat16* xsT   = (__hip_bfloat16*)w;  w += szBig;
    __hip_bfloat16* deT   = (__hip_bfloat16*)w;  w += szBig;
    float*          dbc   = (float*)w;           w += (size_t)BLROWS * 96 * 4;
    float*          dbcP  = (float*)w;           w += (size_t)NSLICE * BLROWS * 96 * 4;
    __hip_bfloat16* dtH   = (__hip_bfloat16*)w;  w += (size_t)BLROWS * DTRANK * 2;
    float*          Bc    = (float*)w;           w += szBc;
    float*          sde   = (float*)w;           w += (size_t)B_SZ * NCHUNK * DINNER * 4;
    __hip_bfloat16* xH    = (__hip_bfloat16*)w;  w += (size_t)BLROWS*DMODEL*2;
    __hip_bfloat16* WinH  = (__hip_bfloat16*)w;  w += (size_t)2*DINNER*DMODEL*2;
    __hip_bfloat16* WxH   = (__hip_bfloat16*)w;  w += (size_t)128*DINNER*2;
    __hip_bfloat16* WdtH  = (__hip_bfloat16*)w;  w += (size_t)DINNER*DTRANK*2;
    __hip_bfloat16* WoutH = (__hip_bfloat16*)w;  w += (size_t)DMODEL*DINNER*2;
    __hip_bfloat16* yN    = xsN;

    // 0) fused init: all casts
    init_kernel<<<GTOT/256, 256, 0, stream>>>(x, W_in, W_x, W_dt, W_out,
        (unsigned short*)xH, (unsigned short*)WinH, (unsigned short*)WxH,
        (unsigned short*)WdtH, (unsigned short*)WoutH);

    // 1) xz = x @ W_in^T -> xbufN | zbufN. 128x128 tiles, 512 blocks (2/CU)
    gemm_tn<128,128,5,false><<<dim3(BLROWS/128, (2*DINNER)/128, 1), 256, 0, stream>>>(
        xH, WinH, BLROWS, 2*DINNER, DMODEL, DMODEL, nullptr, xbufN, zbufN, nullptr);

    // 2) fused conv+silu+transpose: xbufN -> xsN + xsT
    conv_transpose_kernel<<<dim3(SEQ/64, DINNER/64, B_SZ), 256, 0, stream>>>(
        (const unsigned short*)xbufN, conv_w, conv_b,
        (unsigned short*)xsN, (unsigned short*)xsT);

    // 3) dbc partials = x_ssm @ W_x^T (N=96, split-K=16, plain stores; 512 blocks)
    //    then fused reduce + dt cvt
    gemm_tn<128,64,9,true><<<dim3(BLROWS/128, 2, NSLICE), 256, 0, stream>>>(
        xsN, WxH, BLROWS, 96, DINNER, DINNER/NSLICE, dbcP, nullptr, nullptr, nullptr);
    dbc_reduce_kernel<<<BLROWS/2, 192, 0, stream>>>(dbcP, dbc, dtH);

    // 4) delta = softplus(dt @ W_dt^T + b_dt) -> deT (transposed). 512 blocks
    gemm_tn<128,64,8,false><<<dim3(BLROWS/128, DINNER/64, 1), 256, 0, stream>>>(
        dtH, WdtH, BLROWS, DINNER, DTRANK, DTRANK, nullptr, deT, nullptr, b_dt);

    // 5) chunked selective scan, d-per-lane (no LDS, no shuffles). 512 blocks
    scan_pass1<<<B_SZ*NCHUNK*8, 256, 0, stream>>>((const unsigned short*)deT,
        (const unsigned short*)xsT, dbc, A_log, Bc, sde);
    scan_pass2<<<B_SZ*128, 256, 0, stream>>>(Bc, sde, A_log);
    scan_pass3<<<B_SZ*NCHUNK*8, 256, 0, stream>>>((const unsigned short*)deT,
        (const unsigned short*)xsT, dbc, A_log, D_par, Bc,
        (const unsigned short*)zbufN, yN);

    // 6) out = y @ W_out^T -> d_out. 64x64 tiles -> 512 blocks (2/CU), direct f32 store
    gemm_tn<64,64,9,false><<<dim3(BLROWS/64, DMODEL/64, 1), 256, 0, stream>>>(
        yN, WoutH, BLROWS, DMODEL, DINNER, DINNER, (float*)d_out, nullptr, nullptr, nullptr);
}

// Round 7
// 215.178 us; speedup vs baseline: 1.1876x; 1.0680x over previous
//
#include <hip/hip_runtime.h>
#include <hip/hip_bf16.h>

#define B_SZ   2
#define SEQ    1024
#define DMODEL 1024
#define DINNER 2048
#define DSTATE 16
#define DCONV  4
#define DTRANK 64
#define BLROWS (B_SZ*SEQ)
#define NCHUNK 32
#define TCHUNK (SEQ/NCHUNK) // 32
#define NSLICE 16           // dbc split-K partials
#define LOG2E 1.44269504088896f

using floatx4 = __attribute__((ext_vector_type(4))) float;
using short8  = __attribute__((ext_vector_type(8))) short;
using us8     = __attribute__((ext_vector_type(8))) unsigned short;
using us4     = __attribute__((ext_vector_type(4))) unsigned short;

__device__ __forceinline__ float softplus_f(float x) {
    return fmaxf(x, 0.f) + log1pf(__expf(-fabsf(x)));
}
__device__ __forceinline__ float silu_f(float x) {
    return x / (1.f + __expf(-x));
}
__device__ __forceinline__ short bfs(float x) {
    union { __hip_bfloat16 h; short s; } u;
    u.h = __float2bfloat16(x);
    return u.s;
}
__device__ __forceinline__ float b2f(unsigned short s) {
    union { float f; unsigned u; } x;
    x.u = ((unsigned)s) << 16;
    return x.f;
}
__device__ __forceinline__ void gld16(const void* g, void* l) {
    __builtin_amdgcn_global_load_lds((const __attribute__((address_space(1))) void*)g,
                                     (__attribute__((address_space(3))) void*)l,
                                     16, 0, 0);
}
__device__ __forceinline__ void cast8(const float* src, unsigned short* dst, int i) {
    const float* p = src + (size_t)i*8;
    float4 a = *(const float4*)p, b = *(const float4*)(p+4);
    us8 o;
    o[0]=(unsigned short)bfs(a.x); o[1]=(unsigned short)bfs(a.y);
    o[2]=(unsigned short)bfs(a.z); o[3]=(unsigned short)bfs(a.w);
    o[4]=(unsigned short)bfs(b.x); o[5]=(unsigned short)bfs(b.y);
    o[6]=(unsigned short)bfs(b.z); o[7]=(unsigned short)bfs(b.w);
    *(us8*)(dst + (size_t)i*8) = o;
}

// ---------- fused init: 5 casts, range-partitioned ----------
#define G0 (BLROWS*DMODEL/8)       // x cast
#define G1 (2*DINNER*DMODEL/8)     // W_in cast
#define G2 (96*DINNER/8)           // W_x cast
#define G3 (DINNER*DTRANK/8)       // W_dt cast
#define G4 (DMODEL*DINNER/8)       // W_out cast
#define GTOT (G0+G1+G2+G3+G4)
__global__ __launch_bounds__(256)
void init_kernel(const float* __restrict__ x, const float* __restrict__ W_in,
                 const float* __restrict__ W_x, const float* __restrict__ W_dt,
                 const float* __restrict__ W_out,
                 unsigned short* xH, unsigned short* WinH, unsigned short* WxH,
                 unsigned short* WdtH, unsigned short* WoutH)
{
    int i = blockIdx.x*256 + threadIdx.x;
    if (i < G0) { cast8(x, xH, i); return; }            i -= G0;
    if (i < G1) { cast8(W_in, WinH, i); return; }       i -= G1;
    if (i < G2) { cast8(W_x, WxH, i); return; }         i -= G2;
    if (i < G3) { cast8(W_dt, WdtH, i); return; }       i -= G3;
    if (i < G4) { cast8(W_out, WoutH, i); }
}

// ---------- TN MFMA GEMM, double-buffered 2-phase K-loop, tile TM x TN, BK=32 ----------
// EPI: 5 = split col<DINNER -> outH else outH2 (ld DINNER), bf16
//      8 = softplus(v + bias[col]) -> transposed bf16, LDS-transposed coalesced us8
//      9 = plain f32 store to outF + blockIdx.z*M*N (partials / direct out)
template<int TM, int TN, int EPI, bool NGUARD>
__global__ __launch_bounds__(256)
void gemm_tn(const __hip_bfloat16* __restrict__ Ag, const __hip_bfloat16* __restrict__ Bg,
             int M, int N, int K, int kslice,
             float* __restrict__ outF,
             __hip_bfloat16* __restrict__ outH,
             __hip_bfloat16* __restrict__ outH2,
             const float* __restrict__ bias)
{
    constexpr int AG  = TM/64;        // A-tile 64-row stage groups
    constexpr int EB  = TN/64;        // B-tile 64-row stage groups
    constexpr int MF  = TM/32;        // frag-rows per wave
    constexpr int NF  = TN/32;        // frag-cols per wave
    constexpr int SM_SZ = 2*TM*32 + 2*TN*32;
    __shared__ short smem[SM_SZ];
    auto As = (short(*)[TM*32])smem;
    auto Bs = (short(*)[TN*32])(smem + 2*TM*32);

    const int tid  = threadIdx.x;
    const int lane = tid & 63, wave = tid >> 6;
    const int bm0  = blockIdx.x * TM;
    const int bn0  = blockIdx.y * TN;
    const int kbeg = blockIdx.z * kslice;
    const int kend = kbeg + kslice;
    const int wrow = (wave >> 1) * (TM/2), wcol = (wave & 1) * (TN/2);
    const int lrow = lane & 15, quad = lane >> 4;

    const int srow = wave*16 + (lane >> 2);
    const int scol = (lane & 3) * 8;

    const __hip_bfloat16* ga0 = Ag + (size_t)(bm0 + srow)*K      + scol;
    const __hip_bfloat16* ga1 = (AG > 1) ? Ag + (size_t)(bm0 + srow + 64)*K + scol : nullptr;
    const __hip_bfloat16* gb0 = Bg + (size_t)(bn0 + srow)*K      + scol;
    const __hip_bfloat16* gb1 = (EB > 1) ? Bg + (size_t)(bn0 + srow + 64)*K + scol : nullptr;
    const bool b0ok = !NGUARD || (bn0 + wave*16) < N;       // wave-uniform (16-row granules)
    const bool b1ok = (EB > 1) && (!NGUARD || (bn0 + wave*16 + 64) < N);

    auto stage = [&](int c, int k0) {
        gld16(ga0 + k0, &As[c][(wave*16)*32]);
        if (AG > 1) gld16(ga1 + k0, &As[c][(wave*16 + 64)*32]);
        if (b0ok) gld16(gb0 + k0, &Bs[c][(wave*16)*32]);
        if (EB > 1 && b1ok) gld16(gb1 + k0, &Bs[c][(wave*16 + 64)*32]);
    };

    floatx4 acc[MF][NF] = {};

    // prologue: stage first tile, drain, then 2-phase loop (one barrier per K-step)
    stage(0, kbeg);
    __syncthreads();
    int cur = 0;
    for (int k0 = kbeg; k0 < kend; k0 += 32) {
        if (k0 + 32 < kend) stage(cur ^ 1, k0 + 32);   // next-tile loads in flight
        short8 af[MF], bf[NF];
        #pragma unroll
        for (int i = 0; i < MF; i++)
            af[i] = *(const short8*)&As[cur][(wrow + i*16 + lrow)*32 + quad*8];
        #pragma unroll
        for (int j = 0; j < NF; j++)
            bf[j] = *(const short8*)&Bs[cur][(wcol + j*16 + lrow)*32 + quad*8];
        #pragma unroll
        for (int i = 0; i < MF; i++)
            #pragma unroll
            for (int j = 0; j < NF; j++)
                acc[i][j] = __builtin_amdgcn_mfma_f32_16x16x32_bf16(af[i], bf[j], acc[i][j], 0, 0, 0);
        __syncthreads();   // drains next-tile loads (they had MFMA time to land)
        cur ^= 1;
    }

    const int rq = quad * 4;
    if constexpr (EPI == 8) {
        // softplus -> bf16 into LDS transpose buffer t[TN][TM+8], then coalesced us8
        constexpr int TSTR = TM + 8;               // 8-short aligned rows, ~2-way banks
        static_assert(TN*TSTR <= SM_SZ, "transpose buffer fits");
        short* t = smem;
        #pragma unroll
        for (int i = 0; i < MF; i++) {
            #pragma unroll
            for (int j = 0; j < NF; j++) {
                int cl = wcol + j*16 + lrow;       // local d
                int rl = wrow + i*16 + rq;         // local l (us4-aligned)
                us4 pk;
                #pragma unroll
                for (int r = 0; r < 4; r++)
                    pk[r] = (unsigned short)bfs(softplus_f(acc[i][j][r] + bias[bn0 + cl]));
                *(us4*)&t[cl*TSTR + rl] = pk;
            }
        }
        __syncthreads();
        const int bb = bm0 >> 10, lb = bm0 & (SEQ-1);
        constexpr int CPR  = TM/8;                 // us8 chunks per d-row
        constexpr int ITER = (TM*TN)/(256*8);
        #pragma unroll
        for (int it = 0; it < ITER; ++it) {
            int idx = it*256 + tid;
            int dl = idx / CPR, lc = (idx % CPR)*8;
            us8 v = *(const us8*)&t[dl*TSTR + lc];
            *(us8*)((unsigned short*)outH + ((size_t)bb*DINNER + bn0 + dl)*SEQ + lb + lc) = v;
        }
    } else {
        #pragma unroll
        for (int i = 0; i < MF; i++) {
            #pragma unroll
            for (int j = 0; j < NF; j++) {
                int col = bn0 + wcol + j*16 + lrow;
                if (NGUARD && col >= N) continue;
                #pragma unroll
                for (int r = 0; r < 4; r++) {
                    int row = bm0 + wrow + i*16 + rq + r;
                    float v = acc[i][j][r];
                    if constexpr (EPI == 5) {
                        if (col < DINNER)
                            outH[(size_t)row*DINNER + col] = __float2bfloat16(v);
                        else
                            outH2[(size_t)row*DINNER + (col - DINNER)] = __float2bfloat16(v);
                    } else if constexpr (EPI == 9) {
                        outF[(size_t)blockIdx.z*M*N + (size_t)row*N + col] = v;
                    }
                }
            }
        }
    }
}

// ---------- dbc split-K reduce + dt cvt (fused) ----------
__global__ __launch_bounds__(192)
void dbc_reduce_kernel(const float* __restrict__ part, float* __restrict__ dbc,
                       __hip_bfloat16* __restrict__ dtH)
{
    const int tid = threadIdx.x;
    const int r2  = (tid >= 96) ? 1 : 0;
    const int col = tid - 96*r2;
    const int row = blockIdx.x*2 + r2;
    const size_t idx = (size_t)row*96 + col;
    float s = 0.f;
    #pragma unroll
    for (int z = 0; z < NSLICE; z++)
        s += part[(size_t)z*(BLROWS*96) + idx];
    dbc[idx] = s;
    if (col < DTRANK)
        dtH[(size_t)row*DTRANK + col] = __float2bfloat16(s);
}

// ---------- fused conv+silu+transpose: xbufN -> xsN (normal) + xsT (transposed) ----------
__global__ __launch_bounds__(256)
void conv_transpose_kernel(const unsigned short* __restrict__ xbufN,
                           const float* __restrict__ cw,
                           const float* __restrict__ cb,
                           unsigned short* __restrict__ xsN,
                           unsigned short* __restrict__ xsT)
{
    __shared__ unsigned short t[67*68];    // rows l0-3 .. l0+63
    __shared__ unsigned short t2[64*68];
    const int tid = threadIdx.x;
    const int l0 = blockIdx.x * 64, d0 = blockIdx.y * 64, b = blockIdx.z;

    const int lc4 = (tid & 15) * 4;
    for (int r = tid >> 4; r < 67; r += 16) {
        int lg = l0 - 3 + r;
        us4 v = {0,0,0,0};
        if (lg >= 0)
            v = *(const us4*)&xbufN[((size_t)(b*SEQ + lg))*DINNER + d0 + lc4];
        *(us4*)&t[r*68 + lc4] = v;
    }
    __syncthreads();

    const int dd = tid & 63;
    float4 w4 = *(const float4*)&cw[(d0 + dd)*4];
    float  bb = cb[d0 + dd];
    #pragma unroll 4
    for (int rr = tid >> 6; rr < 64; rr += 4) {
        float acc = bb;
        acc += w4.x * b2f(t[(rr+0)*68 + dd]);
        acc += w4.y * b2f(t[(rr+1)*68 + dd]);
        acc += w4.z * b2f(t[(rr+2)*68 + dd]);
        acc += w4.w * b2f(t[(rr+3)*68 + dd]);
        unsigned short h = (unsigned short)bfs(silu_f(acc));
        t2[rr*68 + dd] = h;
        xsN[((size_t)(b*SEQ + l0 + rr))*DINNER + d0 + dd] = h;
    }
    __syncthreads();

    const int dr = tid >> 4, lc = tid & 15;
    #pragma unroll
    for (int i = 0; i < 4; i++) {
        int dT = dr + i*16;
        us4 w;
        #pragma unroll
        for (int j = 0; j < 4; j++)
            w[j] = t2[(lc*4 + j)*68 + dT];
        *(us4*)&xsT[((size_t)b*DINNER + d0 + dT)*SEQ + l0 + lc*4] = w;
    }
}

// ========== chunked selective scan, one d-channel per lane ==========
// grid: B_SZ * NCHUNK * 8 blocks (512); dg = blk&7, c = (blk>>3)&(NCHUNK-1), b = blk>>8
// d = dg*256 + tid. No LDS, no shuffles: h[16] per lane (static unroll), B/C rows
// are wave-uniform -> scalar-pipe loads; z/y path fully coalesced (128B/wave/step).
// Fast path (A_log = log(arange(1..16)) broadcast, verified per-wave):
// exp(de*A[n]) = r^(n+1), r = exp2(-de*LOG2E) -> 1 transcendental + mul chain.
__global__ __launch_bounds__(256)
void scan_pass1(const unsigned short* __restrict__ deT,
                const unsigned short* __restrict__ xsT,
                const float* __restrict__ dbc,
                const float* __restrict__ A_log,
                float* __restrict__ Bc, float* __restrict__ sde)
{
    const int tid = threadIdx.x;
    const int blk = blockIdx.x;
    const int dg  = blk & 7;
    const int c   = (blk >> 3) & (NCHUNK-1);
    const int b   = blk >> 8;
    const int d   = dg*256 + tid;

    float An[16];
    bool okv = true;
    #pragma unroll
    for (int n = 0; n < 16; n++) {
        An[n] = -__expf(A_log[d*DSTATE + n]) * LOG2E;
        okv = okv && (fabsf(An[n] + (float)(n+1)*LOG2E) < 2e-3f*(float)(n+1));
    }
    const bool fast = __all((int)okv);

    size_t rowT = ((size_t)b*DINNER + d)*SEQ;
    const float* brow = dbc + (size_t)b*SEQ*96 + (size_t)(c*TCHUNK)*96 + DTRANK;

    float h[16];
    #pragma unroll
    for (int n = 0; n < 16; n++) h[n] = 0.f;
    float s = 0.f;

    if (fast) {
        for (int t8 = 0; t8 < TCHUNK/8; ++t8) {
            int l0 = c*TCHUNK + t8*8;
            us8 de8 = *(const us8*)&deT[rowT + l0];
            us8 u8  = *(const us8*)&xsT[rowT + l0];
            #pragma unroll
            for (int j2 = 0; j2 < 8; j2++) {
                const float* br = brow + (size_t)(t8*8 + j2)*96;   // wave-uniform
                float de = b2f(de8[j2]);
                float du = de * b2f(u8[j2]);
                float r  = exp2f(de * (-LOG2E));
                float e  = r;
                #pragma unroll
                for (int n = 0; n < 16; n++) {
                    h[n] = e*h[n] + du*br[n];
                    e *= r;
                }
                s += de;
            }
        }
    } else {
        for (int t8 = 0; t8 < TCHUNK/8; ++t8) {
            int l0 = c*TCHUNK + t8*8;
            us8 de8 = *(const us8*)&deT[rowT + l0];
            us8 u8  = *(const us8*)&xsT[rowT + l0];
            #pragma unroll
            for (int j2 = 0; j2 < 8; j2++) {
                const float* br = brow + (size_t)(t8*8 + j2)*96;
                float de = b2f(de8[j2]);
                float du = de * b2f(u8[j2]);
                #pragma unroll
                for (int n = 0; n < 16; n++)
                    h[n] = exp2f(de*An[n])*h[n] + du*br[n];
                s += de;
            }
        }
    }

    size_t ci = (size_t)(b*NCHUNK + c)*DINNER + d;
    #pragma unroll
    for (int n = 0; n < 16; n += 4) {
        float4 v; v.x = h[n]; v.y = h[n+1]; v.z = h[n+2]; v.w = h[n+3];
        *(float4*)&Bc[ci*16 + n] = v;
    }
    sde[ci] = s;
}

__global__ __launch_bounds__(256)
void scan_pass2(float* __restrict__ Bc, const float* __restrict__ sde,
                const float* __restrict__ A_log)
{
    const int tid = threadIdx.x;
    const int n   = tid & 15, dl = tid >> 4;
    const int blk = blockIdx.x;
    const int dg  = blk & 127, b = blk >> 7;
    const int d   = dg*16 + dl;
    const float An = -__expf(A_log[d*DSTATE + n]) * LOG2E;

    float H = 0.f;
    for (int c = 0; c < NCHUNK; ++c) {
        size_t ci = (size_t)(b*NCHUNK + c)*DINNER + d;
        float bc = Bc[ci*16 + n];
        Bc[ci*16 + n] = H;
        H = exp2f(An*sde[ci])*H + bc;
    }
}

// pass3: full recurrence seeded with Hinit, fused gate y = (cc + u*D) * silu(z)
__global__ __launch_bounds__(256)
void scan_pass3(const unsigned short* __restrict__ deT,
                const unsigned short* __restrict__ xsT,
                const float* __restrict__ dbc,
                const float* __restrict__ A_log,
                const float* __restrict__ Dp,
                const float* __restrict__ Hinit,
                const unsigned short* __restrict__ zN,
                __hip_bfloat16* __restrict__ yN)
{
    const int tid = threadIdx.x;
    const int blk = blockIdx.x;
    const int dg  = blk & 7;
    const int c   = (blk >> 3) & (NCHUNK-1);
    const int b   = blk >> 8;
    const int d   = dg*256 + tid;

    float An[16];
    bool okv = true;
    #pragma unroll
    for (int n = 0; n < 16; n++) {
        An[n] = -__expf(A_log[d*DSTATE + n]) * LOG2E;
        okv = okv && (fabsf(An[n] + (float)(n+1)*LOG2E) < 2e-3f*(float)(n+1));
    }
    const bool fast = __all((int)okv);
    const float Dd = Dp[d];

    size_t rowT  = ((size_t)b*DINNER + d)*SEQ;
    size_t baseN = (size_t)b*SEQ*DINNER + d;
    const float* brow = dbc + (size_t)b*SEQ*96 + (size_t)(c*TCHUNK)*96 + DTRANK;

    size_t ci = (size_t)(b*NCHUNK + c)*DINNER + d;
    float h[16];
    #pragma unroll
    for (int n = 0; n < 16; n += 4) {
        float4 v = *(const float4*)&Hinit[ci*16 + n];
        h[n] = v.x; h[n+1] = v.y; h[n+2] = v.z; h[n+3] = v.w;
    }

    if (fast) {
        for (int t8 = 0; t8 < TCHUNK/8; ++t8) {
            int l0 = c*TCHUNK + t8*8;
            us8 de8 = *(const us8*)&deT[rowT + l0];
            us8 u8  = *(const us8*)&xsT[rowT + l0];
            #pragma unroll
            for (int j2 = 0; j2 < 8; j2++) {
                int l = l0 + j2;
                const float* br = brow + (size_t)(t8*8 + j2)*96;   // wave-uniform
                float de = b2f(de8[j2]);
                float u  = b2f(u8[j2]);
                float du = de * u;
                float r  = exp2f(de * (-LOG2E));
                float e  = r, cc = 0.f;
                #pragma unroll
                for (int n = 0; n < 16; n++) {
                    h[n] = e*h[n] + du*br[n];
                    cc  += h[n]*br[DSTATE + n];
                    e   *= r;
                }
                float zv = silu_f(b2f(zN[baseN + (size_t)l*DINNER]));
                yN[baseN + (size_t)l*DINNER] = __float2bfloat16((cc + u*Dd) * zv);
            }
        }
    } else {
        for (int t8 = 0; t8 < TCHUNK/8; ++t8) {
            int l0 = c*TCHUNK + t8*8;
            us8 de8 = *(const us8*)&deT[rowT + l0];
            us8 u8  = *(const us8*)&xsT[rowT + l0];
            #pragma unroll
            for (int j2 = 0; j2 < 8; j2++) {
                int l = l0 + j2;
                const float* br = brow + (size_t)(t8*8 + j2)*96;
                float de = b2f(de8[j2]);
                float u  = b2f(u8[j2]);
                float du = de * u;
                float cc = 0.f;
                #pragma unroll
                for (int n = 0; n < 16; n++) {
                    h[n] = exp2f(de*An[n])*h[n] + du*br[n];
                    cc  += h[n]*br[DSTATE + n];
                }
                float zv = silu_f(b2f(zN[baseN + (size_t)l*DINNER]));
                yN[baseN + (size_t)l*DINNER] = __float2bfloat16((cc + u*Dd) * zv);
            }
        }
    }
}

// ---------- diagnostic fallback ----------
__global__ __launch_bounds__(256)
void zero_out_kernel(float* out, int n) {
    int i = blockIdx.x * 256 + threadIdx.x;
    if (i < n) out[i] = 0.f;
}

extern "C" void kernel_launch(void* const* d_in, const int* in_sizes, int n_in,
                              void* d_out, int out_size, void* d_ws, size_t ws_size,
                              hipStream_t stream) {
    const float* x      = (const float*)d_in[0];
    const float* W_in   = (const float*)d_in[1];
    const float* conv_w = (const float*)d_in[2];
    const float* conv_b = (const float*)d_in[3];
    const float* W_x    = (const float*)d_in[4];
    const float* W_dt   = (const float*)d_in[5];
    const float* b_dt   = (const float*)d_in[6];
    const float* A_log  = (const float*)d_in[7];
    const float* D_par  = (const float*)d_in[8];
    const float* W_out  = (const float*)d_in[9];

    size_t szBig = (size_t)BLROWS * DINNER * 2;                   // 8.39 MB
    size_t szBc  = (size_t)B_SZ * NCHUNK * DINNER * DSTATE * 4;   // 8.39 MB
    size_t need  = 5*szBig                       // xbufN,zbufN,xsN,xsT,deT
                 + (size_t)BLROWS*96*4                        // dbc
                 + (size_t)NSLICE*BLROWS*96*4                 // dbc partials
                 + (size_t)BLROWS*DTRANK*2                    // dtH
                 + szBc + (size_t)B_SZ*NCHUNK*DINNER*4
                 + (size_t)BLROWS*DMODEL*2       // xH
                 + (size_t)2*DINNER*DMODEL*2     // WinH
                 + (size_t)128*DINNER*2          // WxH
                 + (size_t)DINNER*DTRANK*2       // WdtH
                 + (size_t)DMODEL*DINNER*2;      // WoutH   (~83 MB, ws is ~268 MB)

    if (ws_size < need) {
        zero_out_kernel<<<(out_size + 255)/256, 256, 0, stream>>>((float*)d_out, out_size);
        return;
    }

    char* w = (char*)d_ws;
    __hip_bfloat16* xbufN = (__hip_bfloat16*)w;  w += szBig;
    __hip_bfloat16* zbufN = (__hip_bfloat16*)w;  w += szBig;
    __hip_bfloat16* xsN   = (__hip_bfloat16*)w;  w += szBig;   // later y (in-place)
    __hip_bfloat16* xsT   = (__hip_bfloat16*)w;  w += szBig;
    __hip_bfloat16* deT   = (__hip_bfloat16*)w;  w += szBig;
    float*          dbc   = (float*)w;           w += (size_t)BLROWS * 96 * 4;
    float*          dbcP  = (float*)w;           w += (size_t)NSLICE * BLROWS * 96 * 4;
    __hip_bfloat16* dtH   = (__hip_bfloat16*)w;  w += (size_t)BLROWS * DTRANK * 2;
    float*          Bc    = (float*)w;           w += szBc;
    float*          sde   = (float*)w;           w += (size_t)B_SZ * NCHUNK * DINNER * 4;
    __hip_bfloat16* xH    = (__hip_bfloat16*)w;  w += (size_t)BLROWS*DMODEL*2;
    __hip_bfloat16* WinH  = (__hip_bfloat16*)w;  w += (size_t)2*DINNER*DMODEL*2;
    __hip_bfloat16* WxH   = (__hip_bfloat16*)w;  w += (size_t)128*DINNER*2;
    __hip_bfloat16* WdtH  = (__hip_bfloat16*)w;  w += (size_t)DINNER*DTRANK*2;
    __hip_bfloat16* WoutH = (__hip_bfloat16*)w;  w += (size_t)DMODEL*DINNER*2;
    __hip_bfloat16* yN    = xsN;

    // 0) fused init: all casts
    init_kernel<<<GTOT/256, 256, 0, stream>>>(x, W_in, W_x, W_dt, W_out,
        (unsigned short*)xH, (unsigned short*)WinH, (unsigned short*)WxH,
        (unsigned short*)WdtH, (unsigned short*)WoutH);

    // 1) xz = x @ W_in^T -> xbufN | zbufN. 128x128 tiles, 512 blocks (2/CU)
    gemm_tn<128,128,5,false><<<dim3(BLROWS/128, (2*DINNER)/128, 1), 256, 0, stream>>>(
        xH, WinH, BLROWS, 2*DINNER, DMODEL, DMODEL, nullptr, xbufN, zbufN, nullptr);

    // 2) fused conv+silu+transpose: xbufN -> xsN + xsT
    conv_transpose_kernel<<<dim3(SEQ/64, DINNER/64, B_SZ), 256, 0, stream>>>(
        (const unsigned short*)xbufN, conv_w, conv_b,
        (unsigned short*)xsN, (unsigned short*)xsT);

    // 3) dbc partials = x_ssm @ W_x^T (N=96, split-K=16, plain stores; 512 blocks)
    //    then fused reduce + dt cvt
    gemm_tn<128,64,9,true><<<dim3(BLROWS/128, 2, NSLICE), 256, 0, stream>>>(
        xsN, WxH, BLROWS, 96, DINNER, DINNER/NSLICE, dbcP, nullptr, nullptr, nullptr);
    dbc_reduce_kernel<<<BLROWS/2, 192, 0, stream>>>(dbcP, dbc, dtH);

    // 4) delta = softplus(dt @ W_dt^T + b_dt) -> deT via LDS-transpose epilogue.
    //    64x64 tiles -> 1024 blocks (4/CU); K=64 so kernel is epilogue-dominated.
    gemm_tn<64,64,8,false><<<dim3(BLROWS/64, DINNER/64, 1), 256, 0, stream>>>(
        dtH, WdtH, BLROWS, DINNER, DTRANK, DTRANK, nullptr, deT, nullptr, b_dt);

    // 5) chunked selective scan, d-per-lane (no LDS, no shuffles). 512 blocks
    scan_pass1<<<B_SZ*NCHUNK*8, 256, 0, stream>>>((const unsigned short*)deT,
        (const unsigned short*)xsT, dbc, A_log, Bc, sde);
    scan_pass2<<<B_SZ*128, 256, 0, stream>>>(Bc, sde, A_log);
    scan_pass3<<<B_SZ*NCHUNK*8, 256, 0, stream>>>((const unsigned short*)deT,
        (const unsigned short*)xsT, dbc, A_log, D_par, Bc,
        (const unsigned short*)zbufN, yN);

    // 6) out = y @ W_out^T -> d_out. 64x64 tiles -> 512 blocks (2/CU), direct f32 store
    gemm_tn<64,64,9,false><<<dim3(BLROWS/64, DMODEL/64, 1), 256, 0, stream>>>(
        yN, WoutH, BLROWS, DMODEL, DINNER, DINNER, (float*)d_out, nullptr, nullptr, nullptr);
}